// Round 6
// baseline (30099.612 us; speedup 1.0000x reference)
//
#include <hip/hip_runtime.h>
#include <math.h>

#define Bz 16
#define Sz 900
#define Vz 16
#define Dz 256
#define DCz 128
#define Hz 4
#define Nz 6300
#define TSz 5400
#define DSLOTz 145
#define NSLOTz 48
#define GXA 99    // ceil(6300/64) row-blocks for k_kv/k_att
#define GXR 197   // ceil(6300/32) row-blocks for k_read_attn

typedef unsigned short u16;
typedef unsigned int u32;

static __device__ __forceinline__ float sigm(float x){ return 1.0f/(1.0f+__expf(-x)); }
static __device__ __forceinline__ void fma4(float4& a, float s, float4 b){ a.x+=s*b.x; a.y+=s*b.y; a.z+=s*b.z; a.w+=s*b.w; }
static __device__ __forceinline__ float dot4(float4 a, float4 b){ return a.x*b.x + a.y*b.y + a.z*b.z + a.w*b.w; }
static __device__ __forceinline__ float4 f4z(){ float4 z; z.x=0.f; z.y=0.f; z.z=0.f; z.w=0.f; return z; }
static __device__ __forceinline__ float elu1(float x){ return x>0.f ? x+1.f : __expf(x); }
static __device__ __forceinline__ float fcomp(float4 v, int i){ return (i==0)?v.x:(i==1)?v.y:(i==2)?v.z:v.w; }

__global__ void k_sentinel(float* out, int nelem){
  int i = blockIdx.x*256 + threadIdx.x;
  if (i < nelem) out[i] = 12345.0f;
}

__global__ void k_zero(float* p, int n){
  int i = blockIdx.x*256 + threadIdx.x;
  if (i < n) p[i] = 0.f;
}

__global__ void k_rope(float* cost, float* sint){
  int i = blockIdx.x*256 + threadIdx.x;
  if (i >= Nz*32) return;
  int n = i>>5, f = i&31;
  double invd = pow(10000.0, -(double)f/32.0);
  double fr = (double)n * invd;
  cost[i] = (float)cos(fr);
  sint[i] = (float)sin(fr);
}

__global__ void k_embed(const int* __restrict__ di, const int* __restrict__ dq,
                        const int* __restrict__ ti, const float* __restrict__ temb,
                        const float* __restrict__ semb, float* __restrict__ h){
  int i = blockIdx.x*256 + threadIdx.x;   // over B*N*64 float4s
  if (i >= Bz*Nz*64) return;
  int dv = i & 63; int bn = i >> 6; int n = bn % Nz; int b = bn / Nz;
  int tok;
  if (n < TSz){
    int nd = n/1800; int r = n - nd*1800;
    tok = (r < Sz) ? di[(b*3+nd)*Sz + r] : dq[(b*3+nd)*Sz + (r-Sz)];
  } else {
    tok = ti[b*Sz + (n-TSz)];
  }
  const float4* e4 = (const float4*)(temb + (size_t)tok*Dz);
  const float4* s4 = (const float4*)semb;
  float4 v = e4[dv]; float4 s = s4[dv];
  v.x += s.x; v.y += s.y; v.z += s.z; v.w += s.w;
  ((float4*)h)[(size_t)bn*64 + dv] = v;
}

__global__ void k_cache_init(const float* __restrict__ slot_emb, const float* __restrict__ lid,
                             float* __restrict__ cache){
  int i = blockIdx.x*256 + threadIdx.x;
  if (i >= Bz*NSLOTz*DSLOTz) return;
  int c = i % DSLOTz; int sc = (i / DSLOTz) % NSLOTz; int l = sc >> 4;
  float v = 0.f;
  if (c < DCz) v = slot_emb[sc*DCz + c];
  else if (c >= 129 && c < 137) v = lid[l*8 + (c-129)];
  cache[i] = v;
}

__global__ __launch_bounds__(384) void k_proj_cache(const float* __restrict__ cache,
    const float* __restrict__ Wk, const float* __restrict__ Wv,
    float* __restrict__ kread, float* __restrict__ vread){
  __shared__ float crow[DSLOTz];
  int b = blockIdx.x / NSLOTz, sc = blockIdx.x % NSLOTz;
  int t = threadIdx.x;
  const float* cp = cache + (size_t)(b*NSLOTz+sc)*DSLOTz;
  if (t < DSLOTz) crow[t] = cp[t];
  __syncthreads();
  if (t < DCz){
    float a = 0.f;
    for (int r2=0;r2<DSLOTz;r2++) a += crow[r2]*Wk[r2*DCz + t];
    kread[(size_t)(b*NSLOTz+sc)*DCz + t] = a;
  } else {
    int d = t - DCz;
    float a = 0.f;
    for (int r2=0;r2<DSLOTz;r2++) a += crow[r2]*Wv[r2*Dz + d];
    vread[(size_t)(b*NSLOTz+sc)*Dz + d] = a;
  }
}

// read-attention: 32-row tiles, LDS-staged Wq with register prefetch, gate fused.
// LDS: W [0,4096) wT/vT ; H [4096,4672) hT 16x36 ; G [4672,4688) wg ;
//      K [4688,11024) kL 48x132 ; Q [11024,15248) qL 32x132 ; A [15248,16816) attL 32x49
#define RA_W 0
#define RA_H 4096
#define RA_G 4672
#define RA_K 4688
#define RA_Q 11024
#define RA_A 15248
__global__ __launch_bounds__(256) void k_read_attn(
    const float* __restrict__ kread, const float* __restrict__ vread,
    const float* __restrict__ Wq, const float* __restrict__ Wg, const float* __restrict__ bg,
    float* __restrict__ h){
  __shared__ float smem[16816];
  const int t = threadIdx.x;
  const int b = blockIdx.y;
  const int n0 = blockIdx.x*32;
  const int c0 = t&15, rr = t>>4;
  float* hb = h + (size_t)b*Nz*Dz;
  // prefetch tile 0 (regs) before doing the one-time kL staging
  float4 wpre[2]; float4 hpre = f4z(); float gpre = 0.f;
  {
    #pragma unroll
    for (int k=0;k<2;k++){ int id=t+256*k; int wr=id>>5, cf=id&31;
      wpre[k] = ((const float4*)(Wq + (size_t)wr*DCz))[cf]; }
    if (t<128){ int row=t>>2, u=t&3; int n=n0+row;
      hpre = (n<Nz)? ((const float4*)(hb + (size_t)n*Dz))[u] : f4z(); }
    if (t<16) gpre = Wg[t];
  }
  for (int id=t; id<1536; id+=256){
    int s=id>>5, d4=id&31;
    ((float4*)(smem+RA_K))[s*33+d4] = ((const float4*)(kread + ((size_t)b*NSLOTz+s)*DCz))[d4];
  }
  float4 qa[2][2];
  qa[0][0]=f4z(); qa[0][1]=f4z(); qa[1][0]=f4z(); qa[1][1]=f4z();
  float gacc0=0.f, gacc1=0.f;
  for (int kt=0; kt<256; kt+=16){
    __syncthreads();
    #pragma unroll
    for (int k=0;k<2;k++){ int id=t+256*k; int wr=id>>5, cf=id&31;
      ((float4*)(smem+RA_W))[wr*32+cf] = wpre[k]; }
    if (t<128){ int row=t>>2, u=t&3;
      float* hp = smem + RA_H + row;
      hp[(4*u+0)*36]=hpre.x; hp[(4*u+1)*36]=hpre.y; hp[(4*u+2)*36]=hpre.z; hp[(4*u+3)*36]=hpre.w; }
    if (t<16) smem[RA_G+t] = gpre;
    if (kt+16 < 256){
      #pragma unroll
      for (int k=0;k<2;k++){ int id=t+256*k; int wr=id>>5, cf=id&31;
        wpre[k] = ((const float4*)(Wq + (size_t)(kt+16+wr)*DCz))[cf]; }
      if (t<128){ int row=t>>2, u=t&3; int n=n0+row;
        hpre = (n<Nz)? ((const float4*)(hb + (size_t)n*Dz))[((kt+16)>>2)+u] : f4z(); }
      if (t<16) gpre = Wg[kt+16+t];
    }
    __syncthreads();
    for (int kk=0; kk<16; kk++){
      float2 h2 = *(const float2*)(smem + RA_H + kk*36 + 2*rr);
      const float4* wrow = (const float4*)(smem+RA_W) + kk*32;
      float4 w0=wrow[c0], w1=wrow[c0+16];
      float wg = smem[RA_G+kk];
      fma4(qa[0][0],h2.x,w0); fma4(qa[0][1],h2.x,w1);
      fma4(qa[1][0],h2.y,w0); fma4(qa[1][1],h2.y,w1);
      gacc0 += h2.x*wg; gacc1 += h2.y*wg;
    }
  }
  // prefetch v-chunk 0 while qL/scores run
  float4 vpre[4];
  #pragma unroll
  for (int k=0;k<4;k++){ int id=t+256*k; int sr=id>>6, cf=id&63;
    vpre[k] = ((const float4*)(vread + ((size_t)b*NSLOTz + sr)*Dz))[cf]; }
  __syncthreads();
  ((float4*)(smem+RA_Q))[(2*rr+0)*33 + c0]      = qa[0][0];
  ((float4*)(smem+RA_Q))[(2*rr+0)*33 + 16 + c0] = qa[0][1];
  ((float4*)(smem+RA_Q))[(2*rr+1)*33 + c0]      = qa[1][0];
  ((float4*)(smem+RA_Q))[(2*rr+1)*33 + 16 + c0] = qa[1][1];
  __syncthreads();
  {
    int row = t&31, sg = t>>5;
    const float4* q4 = (const float4*)(smem+RA_Q) + row*33;
    for (int ss=0; ss<6; ss++){
      int s = sg*6+ss;
      const float4* k4 = (const float4*)(smem+RA_K) + s*33;
      float a=0.f;
      for (int d4=0; d4<32; d4++) a += dot4(q4[d4], k4[d4]);
      smem[RA_A + row*49 + s] = a*0.088388347648318447f;
    }
  }
  __syncthreads();
  if (t<32){
    float* ar = smem + RA_A + t*49;
    float mx=-1e30f;
    for (int s=0;s<48;s++) mx=fmaxf(mx,ar[s]);
    float su=0.f;
    for (int s=0;s<48;s++){ float e=__expf(ar[s]-mx); ar[s]=e; su+=e; }
    float inv=1.f/su;
    for (int s=0;s<48;s++) ar[s]*=inv;
  }
  // stage chunk 0 into RA_W (free since GEMM done), then barrier covers softmax too
  #pragma unroll
  for (int k=0;k<4;k++){ int id=t+256*k; int sr=id>>6, cf=id&63;
    ((float4*)(smem+RA_W))[sr*64+cf] = vpre[k]; }
  // prefetch chunk 1
  #pragma unroll
  for (int k=0;k<4;k++){ int id=t+256*k; int sr=id>>6, cf=id&63;
    vpre[k] = ((const float4*)(vread + ((size_t)b*NSLOTz + 16+sr)*Dz))[cf]; }
  __syncthreads();
  float4 ov[2][4];
  #pragma unroll
  for (int i=0;i<2;i++){
    #pragma unroll
    for (int j=0;j<4;j++) ov[i][j]=f4z();
  }
  for (int sc=0; sc<3; sc++){
    for (int ss=0; ss<16; ss++){
      int s = sc*16+ss;
      float a0 = smem[RA_A + (2*rr+0)*49 + s];
      float a1 = smem[RA_A + (2*rr+1)*49 + s];
      const float4* vrow = (const float4*)(smem+RA_W) + ss*64;
      float4 v0=vrow[c0], v1=vrow[c0+16], v2=vrow[c0+32], v3=vrow[c0+48];
      fma4(ov[0][0],a0,v0); fma4(ov[0][1],a0,v1); fma4(ov[0][2],a0,v2); fma4(ov[0][3],a0,v3);
      fma4(ov[1][0],a1,v0); fma4(ov[1][1],a1,v1); fma4(ov[1][2],a1,v2); fma4(ov[1][3],a1,v3);
    }
    if (sc<2){
      __syncthreads();
      #pragma unroll
      for (int k=0;k<4;k++){ int id=t+256*k; int sr=id>>6, cf=id&63;
        ((float4*)(smem+RA_W))[sr*64+cf] = vpre[k]; }
      if (sc==0){
        #pragma unroll
        for (int k=0;k<4;k++){ int id=t+256*k; int sr=id>>6, cf=id&63;
          vpre[k] = ((const float4*)(vread + ((size_t)b*NSLOTz + 32+sr)*Dz))[cf]; }
      }
      __syncthreads();
    }
  }
  float g0 = sigm(gacc0 + bg[0]);
  float g1 = sigm(gacc1 + bg[0]);
  #pragma unroll
  for (int i=0;i<2;i++){
    int n = n0 + 2*rr + i;
    if (n < Nz){
      float g = i ? g1 : g0;
      float4* hp = (float4*)(hb + (size_t)n*Dz);
      #pragma unroll
      for (int j=0;j<4;j++){
        float4 hv = hp[c0+16*j];
        float4 o = ov[i][j];
        hv.x += g*o.x; hv.y += g*o.y; hv.z += g*o.z; hv.w += g*o.w;
        hp[c0+16*j] = hv;
      }
    }
  }
}

// k/v projection (Wqkv cols 256..768) + rope/elu + fused kv accumulation.
// 64-row tiles, K-tile 8, register-prefetched staging.
// LDS: W [0,4096) 8x512 ; hT [4096,4640) 8x68 ; P2 reuses kf [0,4352) vh [4352,8704).
__global__ __launch_bounds__(256) void k_kv(const float* __restrict__ h,
    const float* __restrict__ Wl, const float* __restrict__ cost, const float* __restrict__ sint,
    float* __restrict__ kvbuf){
  __shared__ float smem[8704];
  const int t = threadIdx.x;
  const int b = blockIdx.y;
  const int n0 = blockIdx.x*64;
  const int c0 = t&15, rr = t>>4;
  const float* hb = h + (size_t)b*Nz*Dz;
  float4 ka[4][4], va[4][4];
  #pragma unroll
  for (int i=0;i<4;i++){
    #pragma unroll
    for (int j=0;j<4;j++){ ka[i][j]=f4z(); va[i][j]=f4z(); }
  }
  // prefetch tile 0: W 8x512 = 1024 f4 -> 4/thread; h 64x8 = 128 f4 -> t<128
  float4 wpre[4]; float4 hpre = f4z();
  #pragma unroll
  for (int k=0;k<4;k++){ int id=t+256*k; int wr=id>>7, cf=id&127;
    wpre[k] = ((const float4*)(Wl + (size_t)wr*768 + 256))[cf]; }
  if (t<128){ int row=t>>1, u=t&1; int n=n0+row;
    hpre = (n<Nz)? ((const float4*)(hb + (size_t)n*Dz))[u] : f4z(); }
  for (int kt=0; kt<256; kt+=8){
    __syncthreads();
    #pragma unroll
    for (int k=0;k<4;k++){ int id=t+256*k; int wr=id>>7, cf=id&127;
      ((float4*)smem)[wr*128+cf] = wpre[k]; }
    if (t<128){ int row=t>>1, u=t&1;
      float* hp = smem + 4096 + row;
      hp[(4*u+0)*68]=hpre.x; hp[(4*u+1)*68]=hpre.y; hp[(4*u+2)*68]=hpre.z; hp[(4*u+3)*68]=hpre.w; }
    if (kt+8 < 256){
      #pragma unroll
      for (int k=0;k<4;k++){ int id=t+256*k; int wr=id>>7, cf=id&127;
        wpre[k] = ((const float4*)(Wl + (size_t)(kt+8+wr)*768 + 256))[cf]; }
      if (t<128){ int row=t>>1, u=t&1; int n=n0+row;
        hpre = (n<Nz)? ((const float4*)(hb + (size_t)n*Dz))[((kt+8)>>2)+u] : f4z(); }
    }
    __syncthreads();
    for (int kk=0; kk<8; kk++){
      float4 hv = *(const float4*)(smem + 4096 + kk*68 + 4*rr);
      const float4* wrow = (const float4*)smem + kk*128;
      float4 wk0=wrow[c0], wk1=wrow[c0+16], wk2=wrow[c0+32], wk3=wrow[c0+48];
      float4 wv0=wrow[64+c0], wv1=wrow[64+c0+16], wv2=wrow[64+c0+32], wv3=wrow[64+c0+48];
      #pragma unroll
      for (int i=0;i<4;i++){
        float hc = fcomp(hv, i);
        fma4(ka[i][0],hc,wk0); fma4(ka[i][1],hc,wk1); fma4(ka[i][2],hc,wk2); fma4(ka[i][3],hc,wk3);
        fma4(va[i][0],hc,wv0); fma4(va[i][1],hc,wv1); fma4(va[i][2],hc,wv2); fma4(va[i][3],hc,wv3);
      }
    }
  }
  #pragma unroll
  for (int i=0;i<4;i++){
    int n = n0 + 4*rr + i;
    int valid = (n < Nz);
    int nc = valid ? n : 0;
    float co0 = cost[nc*32 + 2*c0], si0 = sint[nc*32 + 2*c0];
    float co1 = cost[nc*32 + 2*c0+1], si1 = sint[nc*32 + 2*c0+1];
    #pragma unroll
    for (int j=0;j<4;j++){
      float4 kin = ka[i][j];
      float r0 = kin.x*co0 - kin.y*si0;
      float r1 = kin.x*si0 + kin.y*co0;
      float r2 = kin.z*co1 - kin.w*si1;
      float r3 = kin.z*si1 + kin.w*co1;
      float4 ko;
      ko.x = valid ? elu1(r0) : 0.f;
      ko.y = valid ? elu1(r1) : 0.f;
      ko.z = valid ? elu1(r2) : 0.f;
      ko.w = valid ? elu1(r3) : 0.f;
      ka[i][j] = ko;
    }
  }
  const int d = t&63, q4 = t>>6;
  float* kvb = kvbuf + (size_t)(b*Hz)*4160;
  #pragma unroll
  for (int g=0; g<4; g++){
    __syncthreads();
    #pragma unroll
    for (int i=0;i<4;i++){
      *(float4*)(smem + (4*rr+i)*68 + 4*c0)        = ka[i][g];
      *(float4*)(smem + 4352 + (4*rr+i)*68 + 4*c0) = va[i][g];
    }
    __syncthreads();
    float4 kvacc[4];
    #pragma unroll
    for (int u=0;u<4;u++) kvacc[u]=f4z();
    float ksl = 0.f;
    for (int row=0; row<64; row++){
      float kd = smem[row*68 + d];
      ksl += kd;
      const float4* vp = (const float4*)(smem + 4352 + row*68);
      #pragma unroll
      for (int u=0;u<4;u++) fma4(kvacc[u], kd, vp[q4*4+u]);
    }
    float* kq = kvb + g*4160;
    #pragma unroll
    for (int u=0;u<4;u++){
      int e = q4*16 + 4*u;
      atomicAdd(&kq[(e+0)*64+d], kvacc[u].x);
      atomicAdd(&kq[(e+1)*64+d], kvacc[u].y);
      atomicAdd(&kq[(e+2)*64+d], kvacc[u].z);
      atomicAdd(&kq[(e+3)*64+d], kvacc[u].w);
    }
    if (q4==0) atomicAdd(&kq[4096+d], ksl);
  }
}

// P[b][h] = kv_h @ Wo_h  (64 x 256, K=64). grid: Bz*Hz blocks.
__global__ __launch_bounds__(256) void k_pmat(const float* __restrict__ kvbuf,
    const float* __restrict__ Wo, float* __restrict__ pmat){
  __shared__ float smem[8448]; // kvL [0,4352) 64x68 ; wT [4352,8448) 16x256
  const int t = threadIdx.x;
  const int bh = blockIdx.x;
  const int hh = bh & 3;
  const int c0 = t&15, rr = t>>4;
  const float* kvp = kvbuf + (size_t)bh*4160;
  for (int id=t; id<4096; id+=256){
    int e=id>>6, d=id&63;
    smem[e*68+d] = kvp[id];
  }
  float4 acc[4][4];
  #pragma unroll
  for (int i=0;i<4;i++){
    #pragma unroll
    for (int j=0;j<4;j++) acc[i][j]=f4z();
  }
  for (int kt=0; kt<64; kt+=16){
    __syncthreads();
    for (int id=t; id<1024; id+=256){
      int wr=id>>6, cf=id&63;
      ((float4*)(smem+4352))[wr*64+cf] = ((const float4*)(Wo + (size_t)(hh*64+kt+wr)*256))[cf];
    }
    __syncthreads();
    for (int kk=0; kk<16; kk++){
      float4 a4 = *(const float4*)(smem + (kt+kk)*68 + 4*rr);
      const float4* wrow = (const float4*)(smem+4352) + kk*64;
      float4 w0=wrow[c0], w1=wrow[c0+16], w2=wrow[c0+32], w3=wrow[c0+48];
      #pragma unroll
      for (int i=0;i<4;i++){
        float ac = fcomp(a4,i);
        fma4(acc[i][0],ac,w0); fma4(acc[i][1],ac,w1); fma4(acc[i][2],ac,w2); fma4(acc[i][3],ac,w3);
      }
    }
  }
  float* Pp = pmat + (size_t)bh*16384;
  #pragma unroll
  for (int i=0;i<4;i++){
    #pragma unroll
    for (int j=0;j<4;j++) ((float4*)Pp)[(4*rr+i)*64 + c0 + 16*j] = acc[i][j];
  }
}

// q projection + rope/elu + z (shuffle) + per-head qz@P GEMM + residual.
// Register-prefetched staging; qzT stride 65 with b128 row-transposed scatter (conflict-free:
// bank classes (c0+rr) mod 8 tile the 32 banks; the old b32 stride-68 scatter was 8-way).
// LDS: W [0,4096) ; hT [4096,5184) 16x68 ; qzT [5184,9344) 64x65 (d-major) ; ksum [9344,9600)
__global__ __launch_bounds__(256) void k_att(
    float* __restrict__ h, const float* __restrict__ Wq768,
    const float* __restrict__ kvbuf, const float* __restrict__ pmat,
    const float* __restrict__ cost, const float* __restrict__ sint){
  __shared__ float smem[9600];
  const int t = threadIdx.x;
  const int b = blockIdx.y;
  const int n0 = blockIdx.x*64;
  const int c0 = t&15, rr = t>>4;
  const int wr0 = t>>6, cf0 = t&63;     // W staging: rows wr0+4k
  const int hrow = t>>2, hu = t&3;      // h staging
  float* hb = h + (size_t)b*Nz*Dz;
  smem[9344 + t] = kvbuf[(size_t)(b*Hz + (t>>6))*4160 + 4096 + (t&63)];
  float4 wpre[4]; float4 hpre;
  #pragma unroll
  for (int k=0;k<4;k++)
    wpre[k] = ((const float4*)(Wq768 + (size_t)(wr0+4*k)*768))[cf0];
  { int n=n0+hrow; hpre = (n<Nz)? ((const float4*)(hb + (size_t)n*Dz))[hu] : f4z(); }
  float4 qa[4][4];
  #pragma unroll
  for (int i=0;i<4;i++){
    #pragma unroll
    for (int j=0;j<4;j++) qa[i][j]=f4z();
  }
  for (int kt=0; kt<256; kt+=16){
    __syncthreads();
    #pragma unroll
    for (int k=0;k<4;k++) ((float4*)smem)[(wr0+4*k)*64+cf0] = wpre[k];
    { float* hp = smem + 4096 + hrow;
      hp[(4*hu+0)*68]=hpre.x; hp[(4*hu+1)*68]=hpre.y; hp[(4*hu+2)*68]=hpre.z; hp[(4*hu+3)*68]=hpre.w; }
    if (kt+16 < 256){
      #pragma unroll
      for (int k=0;k<4;k++)
        wpre[k] = ((const float4*)(Wq768 + (size_t)(kt+16+wr0+4*k)*768))[cf0];
      int n=n0+hrow; hpre = (n<Nz)? ((const float4*)(hb + (size_t)n*Dz))[((kt+16)>>2)+hu] : f4z();
    }
    __syncthreads();
    for (int kk=0; kk<16; kk++){
      float4 hv = *(const float4*)(smem + 4096 + kk*68 + 4*rr);
      const float4* wrow = (const float4*)smem + kk*64;
      float4 w0=wrow[c0], w1=wrow[c0+16], w2=wrow[c0+32], w3=wrow[c0+48];
      #pragma unroll
      for (int i=0;i<4;i++){
        float hc = fcomp(hv, i);
        fma4(qa[i][0],hc,w0); fma4(qa[i][1],hc,w1); fma4(qa[i][2],hc,w2); fma4(qa[i][3],hc,w3);
      }
    }
  }
  // rope + elu (head=j, hd=4c0+q)
  #pragma unroll
  for (int i=0;i<4;i++){
    int n = n0 + 4*rr + i;
    int nc = (n < Nz) ? n : 0;
    float co0 = cost[nc*32 + 2*c0], si0 = sint[nc*32 + 2*c0];
    float co1 = cost[nc*32 + 2*c0+1], si1 = sint[nc*32 + 2*c0+1];
    #pragma unroll
    for (int j=0;j<4;j++){
      float4 qi = qa[i][j];
      float4 qo;
      qo.x = elu1(qi.x*co0 - qi.y*si0);
      qo.y = elu1(qi.x*si0 + qi.y*co0);
      qo.z = elu1(qi.z*co1 - qi.w*si1);
      qo.w = elu1(qi.z*si1 + qi.w*co1);
      qa[i][j] = qo;
    }
  }
  // z = 1/(qf . ksum + 1e-6) per (row,head), butterfly over the 16 c0-lanes; fold into qa
  {
    float p[4][4];
    #pragma unroll
    for (int i=0;i<4;i++)
      #pragma unroll
      for (int j=0;j<4;j++)
        p[i][j] = dot4(qa[i][j], *(const float4*)(smem + 9344 + j*64 + 4*c0));
    #pragma unroll
    for (int m=1; m<16; m<<=1){
      #pragma unroll
      for (int i=0;i<4;i++)
        #pragma unroll
        for (int j=0;j<4;j++)
          p[i][j] += __shfl_xor(p[i][j], m, 64);
    }
    #pragma unroll
    for (int i=0;i<4;i++)
      #pragma unroll
      for (int j=0;j<4;j++){
        float zv = 1.f/(p[i][j] + 1e-6f);
        qa[i][j].x *= zv; qa[i][j].y *= zv; qa[i][j].z *= zv; qa[i][j].w *= zv;
      }
  }
  float4 oa[4][4];
  #pragma unroll
  for (int i=0;i<4;i++){
    #pragma unroll
    for (int j=0;j<4;j++) oa[i][j]=f4z();
  }
  #pragma unroll
  for (int hh=0; hh<4; hh++){
    const float* Ph = pmat + (size_t)(b*Hz+hh)*16384;
    float4 ppre[4];
    #pragma unroll
    for (int k=0;k<4;k++) ppre[k] = ((const float4*)(Ph + (size_t)(wr0+4*k)*256))[cf0];
    __syncthreads();    // prev head compute done: qzT & W free
    // conflict-free scatter: register-transpose rows into b128 stores, stride 65
    #pragma unroll
    for (int q=0;q<4;q++){
      float4 rv;
      rv.x = fcomp(qa[0][hh],q); rv.y = fcomp(qa[1][hh],q);
      rv.z = fcomp(qa[2][hh],q); rv.w = fcomp(qa[3][hh],q);
      *(float4*)(smem + 5184 + (4*c0+q)*65 + 4*rr) = rv;
    }
    for (int kt2=0; kt2<64; kt2+=16){
      if (kt2) __syncthreads();
      #pragma unroll
      for (int k=0;k<4;k++) ((float4*)smem)[(wr0+4*k)*64+cf0] = ppre[k];
      if (kt2+16 < 64){
        #pragma unroll
        for (int k=0;k<4;k++) ppre[k] = ((const float4*)(Ph + (size_t)(kt2+16+wr0+4*k)*256))[cf0];
      }
      __syncthreads();
      for (int kk=0; kk<16; kk++){
        float4 av = *(const float4*)(smem + 5184 + (kt2+kk)*65 + 4*rr);
        const float4* wrow = (const float4*)smem + kk*64;
        float4 w0=wrow[c0], w1=wrow[c0+16], w2=wrow[c0+32], w3=wrow[c0+48];
        #pragma unroll
        for (int i=0;i<4;i++){
          float ac = fcomp(av, i);
          fma4(oa[i][0],ac,w0); fma4(oa[i][1],ac,w1); fma4(oa[i][2],ac,w2); fma4(oa[i][3],ac,w3);
        }
      }
    }
  }
  #pragma unroll
  for (int i=0;i<4;i++){
    int n = n0 + 4*rr + i;
    if (n < Nz){
      float4* hp = (float4*)(hb + (size_t)n*Dz);
      #pragma unroll
      for (int j=0;j<4;j++){
        float4 hv = hp[c0+16*j];
        hv.x += oa[i][j].x; hv.y += oa[i][j].y; hv.z += oa[i][j].z; hv.w += oa[i][j].w;
        hp[c0+16*j] = hv;
      }
    }
  }
}

__global__ __launch_bounds__(256) void k_wkv(const float* __restrict__ h,
    const float* __restrict__ Wwk, const float* __restrict__ Wwv,
    float* __restrict__ wkbuf, float* __restrict__ wvbuf){
  __shared__ float wtL[16*257];
  int t = threadIdx.x;
  int b = blockIdx.y, m0 = blockIdx.x*16;
  const float* hb = h + ((size_t)b*Nz + (Nz-64))*Dz;
  for (int i=t;i<16*Dz;i+=256){ int r=i>>8,c=i&255; wtL[r*257+c] = hb[(size_t)(m0+r)*Dz + c]; }
  __syncthreads();
  int r=t>>4, c0=t&15;
  float4 ak0=f4z(),ak1=f4z(),av0=f4z(),av1=f4z();
  for (int kk=0;kk<Dz;kk++){
    float hv = wtL[r*257+kk];
    const float4* wk4 = (const float4*)(Wwk + (size_t)kk*DCz);
    const float4* wv4 = (const float4*)(Wwv + (size_t)kk*DCz);
    fma4(ak0,hv,wk4[c0]); fma4(ak1,hv,wk4[c0+16]);
    fma4(av0,hv,wv4[c0]); fma4(av1,hv,wv4[c0+16]);
  }
  float4* ok = (float4*)(wkbuf + (size_t)(b*64 + m0+r)*DCz);
  float4* ov = (float4*)(wvbuf + (size_t)(b*64 + m0+r)*DCz);
  ok[c0]=ak0; ok[c0+16]=ak1; ov[c0]=av0; ov[c0+16]=av1;
}

__global__ __launch_bounds__(256) void k_cache_upd(float* __restrict__ cache,
    const float* __restrict__ wkbuf, const float* __restrict__ wvbuf,
    const float* __restrict__ Wwg, const float* __restrict__ bwg,
    int s0, int it, int pas){
  __shared__ float sqL[16*132];
  __shared__ float wkL[64*132];
  __shared__ float wat[16*68];
  __shared__ float ncL[16*132];
  __shared__ float wg[16];
  int t = threadIdx.x; int b = blockIdx.x;
  for (int i=t;i<16*DCz;i+=256){ int k2=i>>7,c=i&127; sqL[k2*132+c] = cache[((size_t)(b*NSLOTz)+s0+k2)*DSLOTz + c]; }
  for (int i=t;i<64*DCz;i+=256){ int m=i>>7,c=i&127; wkL[m*132+c] = wkbuf[(size_t)(b*64+m)*DCz+c]; }
  __syncthreads();
  {
    int k2 = t>>4;
    const float4* s4 = (const float4*)(sqL) + k2*33;
    for (int mm=0;mm<4;mm++){
      int m = (t&15) + 16*mm;
      const float4* k4 = (const float4*)(wkL) + m*33;
      float a=0.f;
      for (int d4=0;d4<32;d4++) a += dot4(s4[d4], k4[d4]);
      wat[k2*68+m] = a * 0.088388347648318447f;
    }
  }
  __syncthreads();
  if (t<16){
    float mx=-1e30f;
    for (int m=0;m<64;m++) mx = fmaxf(mx, wat[t*68+m]);
    float su=0.f;
    for (int m=0;m<64;m++){ float e=__expf(wat[t*68+m]-mx); wat[t*68+m]=e; su+=e; }
    float inv=1.f/su;
    for (int m=0;m<64;m++) wat[t*68+m]*=inv;
  }
  __syncthreads();
  {
    int k2=t>>4, c0=t&15;
    float4 a0=f4z(), a1=f4z();
    const float4* wvg = (const float4*)(wvbuf + (size_t)b*64*DCz);
    for (int m=0;m<64;m++){
      float a = wat[k2*68+m];
      fma4(a0,a,wvg[m*32+c0]); fma4(a1,a,wvg[m*32+c0+16]);
    }
    ((float4*)ncL)[k2*33+c0]=a0; ((float4*)ncL)[k2*33+16+c0]=a1;
  }
  __syncthreads();
  if (t<16){
    float a = bwg[0];
    for (int d2=0; d2<DCz; d2++) a += sqL[t*132+d2]*Wwg[d2] + ncL[t*132+d2]*Wwg[DCz+d2];
    wg[t] = sigm(a);
  }
  __syncthreads();
  for (int i=t;i<16*DCz;i+=256){
    int k2=i>>7,c=i&127;
    cache[((size_t)(b*NSLOTz)+s0+k2)*DSLOTz + c] = sqL[k2*132+c] + wg[k2]*ncL[k2*132+c];
  }
  if (t<16){
    float* cp = cache + ((size_t)(b*NSLOTz)+s0+t)*DSLOTz;
    cp[128] = wg[t];
    cp[137] = (it==0)?1.f:0.f; cp[138] = (it==1)?1.f:0.f; cp[139]=0.f; cp[140]=0.f;
    cp[141] = (pas==0)?1.f:0.f; cp[142] = (pas==1)?1.f:0.f; cp[143]=0.f; cp[144]=0.f;
  }
}

__global__ __launch_bounds__(256) void k_logits(const float* __restrict__ h,
    const float* __restrict__ Wout, const float* __restrict__ bout, float* __restrict__ out){
  __shared__ float hl[16*257];
  int t = threadIdx.x; int row0 = blockIdx.x*16;
  for (int i=t;i<16*Dz;i+=256){
    int rr=i>>8,c=i&255; int row=row0+rr; int b=row/Sz, s=row-b*Sz;
    hl[rr*257+c] = h[((size_t)b*Nz + TSz + s)*Dz + c];
  }
  __syncthreads();
  int rr = t>>4, v = t&15;
  float a = bout[v];
  for (int c=0;c<Dz;c++) a += hl[rr*257+c]*Wout[c*Vz + v];
  out[(size_t)(row0+rr)*Vz + v] = a;
}

__global__ __launch_bounds__(256) void k_feedback(float* __restrict__ h,
    const float* __restrict__ logits0, const float* __restrict__ pae,
    const float* __restrict__ Wfb, const float* __restrict__ bfb){
  __shared__ float trL[16*257];
  __shared__ float paeL[16*257];
  __shared__ int amL[16];
  int t = threadIdx.x; int b = blockIdx.y; int s0 = blockIdx.x*16;
  if (t<16){
    int s = s0+t; int am=0;
    if (s < Sz){
      const float* lg = logits0 + (size_t)(b*Sz+s)*Vz;
      float best = lg[0];
      for (int v=1;v<16;v++){ if (lg[v] > best){ best=lg[v]; am=v; } }
    }
    amL[t]=am;
  }
  for (int i=t;i<16*Dz;i+=256){
    int rr=i>>8,c=i&255; int s=s0+rr;
    trL[rr*257+c] = (s<Sz)? h[((size_t)b*Nz + TSz + s)*Dz + c] : 0.f;
  }
  __syncthreads();
  for (int i=t;i<16*Dz;i+=256){ int rr=i>>8,c=i&255; paeL[rr*257+c] = pae[(size_t)amL[rr]*Dz + c]; }
  __syncthreads();
  int r=t>>4, c0=t&15;
  float4 acc[4]; acc[0]=f4z(); acc[1]=f4z(); acc[2]=f4z(); acc[3]=f4z();
  for (int kk=0;kk<Dz;kk++){
    float xv = trL[r*257+kk];
    const float4* wr = (const float4*)(Wfb + (size_t)kk*Dz);
    fma4(acc[0],xv,wr[c0]); fma4(acc[1],xv,wr[c0+16]); fma4(acc[2],xv,wr[c0+32]); fma4(acc[3],xv,wr[c0+48]);
  }
  for (int kk=0;kk<Dz;kk++){
    float xv = paeL[r*257+kk];
    const float4* wr = (const float4*)(Wfb + (size_t)(Dz+kk)*Dz);
    fma4(acc[0],xv,wr[c0]); fma4(acc[1],xv,wr[c0+16]); fma4(acc[2],xv,wr[c0+32]); fma4(acc[3],xv,wr[c0+48]);
  }
  int s = s0+r;
  if (s < Sz){
    float* cp = h + ((size_t)b*Nz + TSz + s)*Dz;
    #pragma unroll
    for (int j=0;j<4;j++){
      float vals[4] = {acc[j].x, acc[j].y, acc[j].z, acc[j].w};
      #pragma unroll
      for (int q2=0;q2<4;q2++){
        int c = (c0+16*j)*4 + q2;
        float g = sigm(vals[q2] + bfb[c]);
        cp[c] = trL[r*257+c] + g*paeL[r*257+c];
      }
    }
  }
}

extern "C" void kernel_launch(void* const* d_in, const int* in_sizes, int n_in,
                              void* d_out, int out_size, void* d_ws, size_t ws_size,
                              hipStream_t stream){
  (void)in_sizes; (void)n_in;
  const int*   demo_in   = (const int*)d_in[0];
  const int*   demo_out  = (const int*)d_in[1];
  const int*   test_in   = (const int*)d_in[2];
  const float* token_emb = (const float*)d_in[3];
  const float* seg_emb   = (const float*)d_in[4];
  const float* slot_emb  = (const float*)d_in[5];
  const float* lid_emb   = (const float*)d_in[6];
  const float* Wq_read   = (const float*)d_in[7];
  const float* Wk_read   = (const float*)d_in[8];
  const float* Wv_read   = (const float*)d_in[9];
  const float* Wg_read   = (const float*)d_in[10];
  const float* bg_read   = (const float*)d_in[11];
  const float* Wqkv      = (const float*)d_in[12];
  const float* Wo        = (const float*)d_in[13];
  const float* Wwk       = (const float*)d_in[14];
  const float* Wwv       = (const float*)d_in[15];
  const float* Wwg       = (const float*)d_in[16];
  const float* bwg       = (const float*)d_in[17];
  const float* Wout      = (const float*)d_in[18];
  const float* bout      = (const float*)d_in[19];
  const float* pae       = (const float*)d_in[20];
  const float* Wfb       = (const float*)d_in[21];
  const float* bfb       = (const float*)d_in[22];

  char* wsb = (char*)d_ws;
  size_t off = 0;
  auto alloc = [&](size_t bytes)->char*{
    char* p = wsb + off;
    off += (bytes + 255) & ~(size_t)255;
    return p;
  };
  float* hbuf   = (float*)alloc((size_t)Bz*Nz*Dz*4);
  float* kread  = (float*)alloc((size_t)Bz*NSLOTz*DCz*4);
  float* vread  = (float*)alloc((size_t)Bz*NSLOTz*Dz*4);
  float* cache  = (float*)alloc((size_t)Bz*NSLOTz*DSLOTz*4);
  float* kvbuf  = (float*)alloc((size_t)Bz*Hz*4160*4);
  float* pmat   = (float*)alloc((size_t)Bz*Hz*64*256*4);
  float* wkbuf  = (float*)alloc((size_t)Bz*64*DCz*4);
  float* wvbuf  = (float*)alloc((size_t)Bz*64*DCz*4);
  float* logits0= (float*)alloc((size_t)Bz*Sz*Vz*4);
  float* cost   = (float*)alloc((size_t)Nz*32*4);
  float* sint   = (float*)alloc((size_t)Nz*32*4);

  if (off > ws_size){
    k_sentinel<<<(out_size+255)/256, 256, 0, stream>>>((float*)d_out, out_size);
    return;
  }

  k_rope<<<(Nz*32+255)/256, 256, 0, stream>>>(cost, sint);
  k_cache_init<<<(Bz*NSLOTz*DSLOTz+255)/256, 256, 0, stream>>>(slot_emb, lid_emb, cache);

  const int KVN = Bz*Hz*4160;
  for (int pas=0; pas<2; pas++){
    k_embed<<<(Bz*Nz*64+255)/256, 256, 0, stream>>>(demo_in, demo_out, test_in, token_emb, seg_emb, hbuf);
    if (pas==1)
      k_feedback<<<dim3(57,Bz), 256, 0, stream>>>(hbuf, logits0, pae, Wfb, bfb);
    for (int l=0; l<3; l++){
      for (int it=0; it<2; it++){
        k_proj_cache<<<Bz*NSLOTz, 384, 0, stream>>>(cache,
            Wk_read + (size_t)l*DSLOTz*DCz, Wv_read + (size_t)l*DSLOTz*Dz, kread, vread);
        k_read_attn<<<dim3(GXR,Bz), 256, 0, stream>>>(kread, vread,
            Wq_read + (size_t)l*Dz*DCz, Wg_read + (size_t)l*Dz, bg_read + l, hbuf);
        k_zero<<<(KVN+255)/256, 256, 0, stream>>>(kvbuf, KVN);
        k_kv<<<dim3(GXA,Bz), 256, 0, stream>>>(hbuf,
            Wqkv + (size_t)l*Dz*768, cost, sint, kvbuf);
        k_pmat<<<Bz*Hz, 256, 0, stream>>>(kvbuf, Wo + (size_t)l*Dz*Dz, pmat);
        k_att<<<dim3(GXA,Bz), 256, 0, stream>>>(hbuf,
            Wqkv + (size_t)l*Dz*768, kvbuf, pmat, cost, sint);
        k_wkv<<<dim3(4,Bz), 256, 0, stream>>>(hbuf,
            Wwk + (size_t)l*Dz*DCz, Wwv + (size_t)l*Dz*DCz, wkbuf, wvbuf);
        k_cache_upd<<<Bz, 256, 0, stream>>>(cache, wkbuf, wvbuf,
            Wwg + (size_t)l*2*DCz, bwg + l, l*16, it, pas);
      }
    }
    float* outp = (pas==0) ? logits0 : (float*)d_out;
    k_logits<<<900, 256, 0, stream>>>(hbuf, Wout, bout, outp);
  }
}

// Round 7
// 19981.183 us; speedup vs baseline: 1.5064x; 1.5064x over previous
//
#include <hip/hip_runtime.h>
#include <math.h>

#define Bz 16
#define Sz 900
#define Vz 16
#define Dz 256
#define DCz 128
#define Hz 4
#define Nz 6300
#define TSz 5400
#define DSLOTz 145
#define NSLOTz 48
#define GXA 99    // ceil(6300/64) row-blocks for k_kv/k_att
#define GXR 197   // ceil(6300/32) row-blocks for k_read_attn

typedef unsigned short u16;
typedef unsigned int u32;

static __device__ __forceinline__ float sigm(float x){ return 1.0f/(1.0f+__expf(-x)); }
static __device__ __forceinline__ void fma4(float4& a, float s, float4 b){ a.x+=s*b.x; a.y+=s*b.y; a.z+=s*b.z; a.w+=s*b.w; }
static __device__ __forceinline__ float dot4(float4 a, float4 b){ return a.x*b.x + a.y*b.y + a.z*b.z + a.w*b.w; }
static __device__ __forceinline__ float4 f4z(){ float4 z; z.x=0.f; z.y=0.f; z.z=0.f; z.w=0.f; return z; }
static __device__ __forceinline__ float elu1(float x){ return x>0.f ? x+1.f : __expf(x); }
static __device__ __forceinline__ float fcomp(float4 v, int i){ return (i==0)?v.x:(i==1)?v.y:(i==2)?v.z:v.w; }

__global__ void k_sentinel(float* out, int nelem){
  int i = blockIdx.x*256 + threadIdx.x;
  if (i < nelem) out[i] = 12345.0f;
}

__global__ void k_zero(float* p, int n){
  int i = blockIdx.x*256 + threadIdx.x;
  if (i < n) p[i] = 0.f;
}

__global__ void k_rope(float* cost, float* sint){
  int i = blockIdx.x*256 + threadIdx.x;
  if (i >= Nz*32) return;
  int n = i>>5, f = i&31;
  double invd = pow(10000.0, -(double)f/32.0);
  double fr = (double)n * invd;
  cost[i] = (float)cos(fr);
  sint[i] = (float)sin(fr);
}

__global__ void k_embed(const int* __restrict__ di, const int* __restrict__ dq,
                        const int* __restrict__ ti, const float* __restrict__ temb,
                        const float* __restrict__ semb, float* __restrict__ h){
  int i = blockIdx.x*256 + threadIdx.x;   // over B*N*64 float4s
  if (i >= Bz*Nz*64) return;
  int dv = i & 63; int bn = i >> 6; int n = bn % Nz; int b = bn / Nz;
  int tok;
  if (n < TSz){
    int nd = n/1800; int r = n - nd*1800;
    tok = (r < Sz) ? di[(b*3+nd)*Sz + r] : dq[(b*3+nd)*Sz + (r-Sz)];
  } else {
    tok = ti[b*Sz + (n-TSz)];
  }
  const float4* e4 = (const float4*)(temb + (size_t)tok*Dz);
  const float4* s4 = (const float4*)semb;
  float4 v = e4[dv]; float4 s = s4[dv];
  v.x += s.x; v.y += s.y; v.z += s.z; v.w += s.w;
  ((float4*)h)[(size_t)bn*64 + dv] = v;
}

__global__ void k_cache_init(const float* __restrict__ slot_emb, const float* __restrict__ lid,
                             float* __restrict__ cache){
  int i = blockIdx.x*256 + threadIdx.x;
  if (i >= Bz*NSLOTz*DSLOTz) return;
  int c = i % DSLOTz; int sc = (i / DSLOTz) % NSLOTz; int l = sc >> 4;
  float v = 0.f;
  if (c < DCz) v = slot_emb[sc*DCz + c];
  else if (c >= 129 && c < 137) v = lid[l*8 + (c-129)];
  cache[i] = v;
}

__global__ __launch_bounds__(384) void k_proj_cache(const float* __restrict__ cache,
    const float* __restrict__ Wk, const float* __restrict__ Wv,
    float* __restrict__ kread, float* __restrict__ vread){
  __shared__ float crow[DSLOTz];
  int b = blockIdx.x / NSLOTz, sc = blockIdx.x % NSLOTz;
  int t = threadIdx.x;
  const float* cp = cache + (size_t)(b*NSLOTz+sc)*DSLOTz;
  if (t < DSLOTz) crow[t] = cp[t];
  __syncthreads();
  if (t < DCz){
    float a = 0.f;
    for (int r2=0;r2<DSLOTz;r2++) a += crow[r2]*Wk[r2*DCz + t];
    kread[(size_t)(b*NSLOTz+sc)*DCz + t] = a;
  } else {
    int d = t - DCz;
    float a = 0.f;
    for (int r2=0;r2<DSLOTz;r2++) a += crow[r2]*Wv[r2*Dz + d];
    vread[(size_t)(b*NSLOTz+sc)*Dz + d] = a;
  }
}

// read-attention: 32-row tiles, LDS-staged Wq (K-tile 16), gate fused in GEMM.
// (round-5 version — round-6 register prefetch spilled: VGPR 256, 1.5GB scratch traffic)
// LDS: W [0,4096) wT/vT ; H [4096,4672) hT 16x36 ; G [4672,4688) wg ;
//      K [4688,11024) kL 48x132 ; Q [11024,15248) qL 32x132 ; A [15248,16816) attL 32x49
#define RA_W 0
#define RA_H 4096
#define RA_G 4672
#define RA_K 4688
#define RA_Q 11024
#define RA_A 15248
__global__ __launch_bounds__(256) void k_read_attn(
    const float* __restrict__ kread, const float* __restrict__ vread,
    const float* __restrict__ Wq, const float* __restrict__ Wg, const float* __restrict__ bg,
    float* __restrict__ h){
  __shared__ float smem[16816];
  const int t = threadIdx.x;
  const int b = blockIdx.y;
  const int n0 = blockIdx.x*32;
  const int c0 = t&15, rr = t>>4;
  float* hb = h + (size_t)b*Nz*Dz;
  for (int id=t; id<1536; id+=256){
    int s=id>>5, d4=id&31;
    ((float4*)(smem+RA_K))[s*33+d4] = ((const float4*)(kread + ((size_t)b*NSLOTz+s)*DCz))[d4];
  }
  float4 qa[2][2];
  qa[0][0]=f4z(); qa[0][1]=f4z(); qa[1][0]=f4z(); qa[1][1]=f4z();
  float gacc0=0.f, gacc1=0.f;
  for (int kt=0; kt<256; kt+=16){
    __syncthreads();
    for (int id=t; id<512; id+=256){
      int wr=id>>5, cf=id&31;
      ((float4*)(smem+RA_W))[wr*32+cf] = ((const float4*)(Wq + (size_t)(kt+wr)*DCz))[cf];
    }
    if (t<128){
      int row=t>>2, u=t&3;
      int n=n0+row;
      float4 hv = (n<Nz)? ((const float4*)(hb + (size_t)n*Dz))[(kt>>2)+u] : f4z();
      float* hp = smem + RA_H + row;
      hp[(4*u+0)*36]=hv.x; hp[(4*u+1)*36]=hv.y; hp[(4*u+2)*36]=hv.z; hp[(4*u+3)*36]=hv.w;
    }
    if (t<16) smem[RA_G+t] = Wg[kt+t];
    __syncthreads();
    for (int kk=0; kk<16; kk++){
      float2 h2 = *(const float2*)(smem + RA_H + kk*36 + 2*rr);
      const float4* wrow = (const float4*)(smem+RA_W) + kk*32;
      float4 w0=wrow[c0], w1=wrow[c0+16];
      float wg = smem[RA_G+kk];
      fma4(qa[0][0],h2.x,w0); fma4(qa[0][1],h2.x,w1);
      fma4(qa[1][0],h2.y,w0); fma4(qa[1][1],h2.y,w1);
      gacc0 += h2.x*wg; gacc1 += h2.y*wg;
    }
  }
  __syncthreads();
  ((float4*)(smem+RA_Q))[(2*rr+0)*33 + c0]      = qa[0][0];
  ((float4*)(smem+RA_Q))[(2*rr+0)*33 + 16 + c0] = qa[0][1];
  ((float4*)(smem+RA_Q))[(2*rr+1)*33 + c0]      = qa[1][0];
  ((float4*)(smem+RA_Q))[(2*rr+1)*33 + 16 + c0] = qa[1][1];
  __syncthreads();
  {
    int row = t&31, sg = t>>5;
    const float4* q4 = (const float4*)(smem+RA_Q) + row*33;
    for (int ss=0; ss<6; ss++){
      int s = sg*6+ss;
      const float4* k4 = (const float4*)(smem+RA_K) + s*33;
      float a=0.f;
      for (int d4=0; d4<32; d4++) a += dot4(q4[d4], k4[d4]);
      smem[RA_A + row*49 + s] = a*0.088388347648318447f;
    }
  }
  __syncthreads();
  if (t<32){
    float* ar = smem + RA_A + t*49;
    float mx=-1e30f;
    for (int s=0;s<48;s++) mx=fmaxf(mx,ar[s]);
    float su=0.f;
    for (int s=0;s<48;s++){ float e=__expf(ar[s]-mx); ar[s]=e; su+=e; }
    float inv=1.f/su;
    for (int s=0;s<48;s++) ar[s]*=inv;
  }
  float4 ov[2][4];
  #pragma unroll
  for (int i=0;i<2;i++){
    #pragma unroll
    for (int j=0;j<4;j++) ov[i][j]=f4z();
  }
  for (int sc=0; sc<3; sc++){
    __syncthreads();
    for (int id=t; id<1024; id+=256){
      int sr=id>>6, cf=id&63;
      ((float4*)(smem+RA_W))[sr*64+cf] = ((const float4*)(vread + ((size_t)b*NSLOTz + sc*16+sr)*Dz))[cf];
    }
    __syncthreads();
    for (int ss=0; ss<16; ss++){
      int s = sc*16+ss;
      float a0 = smem[RA_A + (2*rr+0)*49 + s];
      float a1 = smem[RA_A + (2*rr+1)*49 + s];
      const float4* vrow = (const float4*)(smem+RA_W) + ss*64;
      float4 v0=vrow[c0], v1=vrow[c0+16], v2=vrow[c0+32], v3=vrow[c0+48];
      fma4(ov[0][0],a0,v0); fma4(ov[0][1],a0,v1); fma4(ov[0][2],a0,v2); fma4(ov[0][3],a0,v3);
      fma4(ov[1][0],a1,v0); fma4(ov[1][1],a1,v1); fma4(ov[1][2],a1,v2); fma4(ov[1][3],a1,v3);
    }
  }
  float g0 = sigm(gacc0 + bg[0]);
  float g1 = sigm(gacc1 + bg[0]);
  #pragma unroll
  for (int i=0;i<2;i++){
    int n = n0 + 2*rr + i;
    if (n < Nz){
      float g = i ? g1 : g0;
      float4* hp = (float4*)(hb + (size_t)n*Dz);
      #pragma unroll
      for (int j=0;j<4;j++){
        float4 hv = hp[c0+16*j];
        float4 o = ov[i][j];
        hv.x += g*o.x; hv.y += g*o.y; hv.z += g*o.z; hv.w += g*o.w;
        hp[c0+16*j] = hv;
      }
    }
  }
}

// k/v projection (Wqkv cols 256..768) + rope/elu + fused kv accumulation.
// 64-row tiles, K-tile 8, register-prefetched staging (no spill: VGPR 124).
// LDS: W [0,4096) 8x512 ; hT [4096,4640) 8x68 ; P2 reuses kf [0,4352) vh [4352,8704).
__global__ __launch_bounds__(256) void k_kv(const float* __restrict__ h,
    const float* __restrict__ Wl, const float* __restrict__ cost, const float* __restrict__ sint,
    float* __restrict__ kvbuf){
  __shared__ float smem[8704];
  const int t = threadIdx.x;
  const int b = blockIdx.y;
  const int n0 = blockIdx.x*64;
  const int c0 = t&15, rr = t>>4;
  const float* hb = h + (size_t)b*Nz*Dz;
  float4 ka[4][4], va[4][4];
  #pragma unroll
  for (int i=0;i<4;i++){
    #pragma unroll
    for (int j=0;j<4;j++){ ka[i][j]=f4z(); va[i][j]=f4z(); }
  }
  float4 wpre[4]; float4 hpre = f4z();
  #pragma unroll
  for (int k=0;k<4;k++){ int id=t+256*k; int wr=id>>7, cf=id&127;
    wpre[k] = ((const float4*)(Wl + (size_t)wr*768 + 256))[cf]; }
  if (t<128){ int row=t>>1, u=t&1; int n=n0+row;
    hpre = (n<Nz)? ((const float4*)(hb + (size_t)n*Dz))[u] : f4z(); }
  for (int kt=0; kt<256; kt+=8){
    __syncthreads();
    #pragma unroll
    for (int k=0;k<4;k++){ int id=t+256*k; int wr=id>>7, cf=id&127;
      ((float4*)smem)[wr*128+cf] = wpre[k]; }
    if (t<128){ int row=t>>1, u=t&1;
      float* hp = smem + 4096 + row;
      hp[(4*u+0)*68]=hpre.x; hp[(4*u+1)*68]=hpre.y; hp[(4*u+2)*68]=hpre.z; hp[(4*u+3)*68]=hpre.w; }
    if (kt+8 < 256){
      #pragma unroll
      for (int k=0;k<4;k++){ int id=t+256*k; int wr=id>>7, cf=id&127;
        wpre[k] = ((const float4*)(Wl + (size_t)(kt+8+wr)*768 + 256))[cf]; }
      if (t<128){ int row=t>>1, u=t&1; int n=n0+row;
        hpre = (n<Nz)? ((const float4*)(hb + (size_t)n*Dz))[((kt+8)>>2)+u] : f4z(); }
    }
    __syncthreads();
    for (int kk=0; kk<8; kk++){
      float4 hv = *(const float4*)(smem + 4096 + kk*68 + 4*rr);
      const float4* wrow = (const float4*)smem + kk*128;
      float4 wk0=wrow[c0], wk1=wrow[c0+16], wk2=wrow[c0+32], wk3=wrow[c0+48];
      float4 wv0=wrow[64+c0], wv1=wrow[64+c0+16], wv2=wrow[64+c0+32], wv3=wrow[64+c0+48];
      #pragma unroll
      for (int i=0;i<4;i++){
        float hc = fcomp(hv, i);
        fma4(ka[i][0],hc,wk0); fma4(ka[i][1],hc,wk1); fma4(ka[i][2],hc,wk2); fma4(ka[i][3],hc,wk3);
        fma4(va[i][0],hc,wv0); fma4(va[i][1],hc,wv1); fma4(va[i][2],hc,wv2); fma4(va[i][3],hc,wv3);
      }
    }
  }
  #pragma unroll
  for (int i=0;i<4;i++){
    int n = n0 + 4*rr + i;
    int valid = (n < Nz);
    int nc = valid ? n : 0;
    float co0 = cost[nc*32 + 2*c0], si0 = sint[nc*32 + 2*c0];
    float co1 = cost[nc*32 + 2*c0+1], si1 = sint[nc*32 + 2*c0+1];
    #pragma unroll
    for (int j=0;j<4;j++){
      float4 kin = ka[i][j];
      float r0 = kin.x*co0 - kin.y*si0;
      float r1 = kin.x*si0 + kin.y*co0;
      float r2 = kin.z*co1 - kin.w*si1;
      float r3 = kin.z*si1 + kin.w*co1;
      float4 ko;
      ko.x = valid ? elu1(r0) : 0.f;
      ko.y = valid ? elu1(r1) : 0.f;
      ko.z = valid ? elu1(r2) : 0.f;
      ko.w = valid ? elu1(r3) : 0.f;
      ka[i][j] = ko;
    }
  }
  const int d = t&63, q4 = t>>6;
  float* kvb = kvbuf + (size_t)(b*Hz)*4160;
  #pragma unroll
  for (int g=0; g<4; g++){
    __syncthreads();
    #pragma unroll
    for (int i=0;i<4;i++){
      *(float4*)(smem + (4*rr+i)*68 + 4*c0)        = ka[i][g];
      *(float4*)(smem + 4352 + (4*rr+i)*68 + 4*c0) = va[i][g];
    }
    __syncthreads();
    float4 kvacc[4];
    #pragma unroll
    for (int u=0;u<4;u++) kvacc[u]=f4z();
    float ksl = 0.f;
    for (int row=0; row<64; row++){
      float kd = smem[row*68 + d];
      ksl += kd;
      const float4* vp = (const float4*)(smem + 4352 + row*68);
      #pragma unroll
      for (int u=0;u<4;u++) fma4(kvacc[u], kd, vp[q4*4+u]);
    }
    float* kq = kvb + g*4160;
    #pragma unroll
    for (int u=0;u<4;u++){
      int e = q4*16 + 4*u;
      atomicAdd(&kq[(e+0)*64+d], kvacc[u].x);
      atomicAdd(&kq[(e+1)*64+d], kvacc[u].y);
      atomicAdd(&kq[(e+2)*64+d], kvacc[u].z);
      atomicAdd(&kq[(e+3)*64+d], kvacc[u].w);
    }
    if (q4==0) atomicAdd(&kq[4096+d], ksl);
  }
}

// P[b][h] = kv_h @ Wo_h  (64 x 256, K=64). grid: Bz*Hz blocks.
__global__ __launch_bounds__(256) void k_pmat(const float* __restrict__ kvbuf,
    const float* __restrict__ Wo, float* __restrict__ pmat){
  __shared__ float smem[8448]; // kvL [0,4352) 64x68 ; wT [4352,8448) 16x256
  const int t = threadIdx.x;
  const int bh = blockIdx.x;
  const int hh = bh & 3;
  const int c0 = t&15, rr = t>>4;
  const float* kvp = kvbuf + (size_t)bh*4160;
  for (int id=t; id<4096; id+=256){
    int e=id>>6, d=id&63;
    smem[e*68+d] = kvp[id];
  }
  float4 acc[4][4];
  #pragma unroll
  for (int i=0;i<4;i++){
    #pragma unroll
    for (int j=0;j<4;j++) acc[i][j]=f4z();
  }
  for (int kt=0; kt<64; kt+=16){
    __syncthreads();
    for (int id=t; id<1024; id+=256){
      int wr=id>>6, cf=id&63;
      ((float4*)(smem+4352))[wr*64+cf] = ((const float4*)(Wo + (size_t)(hh*64+kt+wr)*256))[cf];
    }
    __syncthreads();
    for (int kk=0; kk<16; kk++){
      float4 a4 = *(const float4*)(smem + (kt+kk)*68 + 4*rr);
      const float4* wrow = (const float4*)(smem+4352) + kk*64;
      float4 w0=wrow[c0], w1=wrow[c0+16], w2=wrow[c0+32], w3=wrow[c0+48];
      #pragma unroll
      for (int i=0;i<4;i++){
        float ac = fcomp(a4,i);
        fma4(acc[i][0],ac,w0); fma4(acc[i][1],ac,w1); fma4(acc[i][2],ac,w2); fma4(acc[i][3],ac,w3);
      }
    }
  }
  float* Pp = pmat + (size_t)bh*16384;
  #pragma unroll
  for (int i=0;i<4;i++){
    #pragma unroll
    for (int j=0;j<4;j++) ((float4*)Pp)[(4*rr+i)*64 + c0 + 16*j] = acc[i][j];
  }
}

// q projection + rope/elu + z (shuffle) + per-head qz@P GEMM + residual.
// Register-prefetched staging; qzT stride 65 with b128 row-transposed scatter (conflict-free).
// LDS: W [0,4096) ; hT [4096,5184) 16x68 ; qzT [5184,9344) 64x65 (d-major) ; ksum [9344,9600)
__global__ __launch_bounds__(256) void k_att(
    float* __restrict__ h, const float* __restrict__ Wq768,
    const float* __restrict__ kvbuf, const float* __restrict__ pmat,
    const float* __restrict__ cost, const float* __restrict__ sint){
  __shared__ float smem[9600];
  const int t = threadIdx.x;
  const int b = blockIdx.y;
  const int n0 = blockIdx.x*64;
  const int c0 = t&15, rr = t>>4;
  const int wr0 = t>>6, cf0 = t&63;     // W staging: rows wr0+4k
  const int hrow = t>>2, hu = t&3;      // h staging
  float* hb = h + (size_t)b*Nz*Dz;
  smem[9344 + t] = kvbuf[(size_t)(b*Hz + (t>>6))*4160 + 4096 + (t&63)];
  float4 wpre[4]; float4 hpre;
  #pragma unroll
  for (int k=0;k<4;k++)
    wpre[k] = ((const float4*)(Wq768 + (size_t)(wr0+4*k)*768))[cf0];
  { int n=n0+hrow; hpre = (n<Nz)? ((const float4*)(hb + (size_t)n*Dz))[hu] : f4z(); }
  float4 qa[4][4];
  #pragma unroll
  for (int i=0;i<4;i++){
    #pragma unroll
    for (int j=0;j<4;j++) qa[i][j]=f4z();
  }
  for (int kt=0; kt<256; kt+=16){
    __syncthreads();
    #pragma unroll
    for (int k=0;k<4;k++) ((float4*)smem)[(wr0+4*k)*64+cf0] = wpre[k];
    { float* hp = smem + 4096 + hrow;
      hp[(4*hu+0)*68]=hpre.x; hp[(4*hu+1)*68]=hpre.y; hp[(4*hu+2)*68]=hpre.z; hp[(4*hu+3)*68]=hpre.w; }
    if (kt+16 < 256){
      #pragma unroll
      for (int k=0;k<4;k++)
        wpre[k] = ((const float4*)(Wq768 + (size_t)(kt+16+wr0+4*k)*768))[cf0];
      int n=n0+hrow; hpre = (n<Nz)? ((const float4*)(hb + (size_t)n*Dz))[((kt+16)>>2)+hu] : f4z();
    }
    __syncthreads();
    for (int kk=0; kk<16; kk++){
      float4 hv = *(const float4*)(smem + 4096 + kk*68 + 4*rr);
      const float4* wrow = (const float4*)smem + kk*64;
      float4 w0=wrow[c0], w1=wrow[c0+16], w2=wrow[c0+32], w3=wrow[c0+48];
      #pragma unroll
      for (int i=0;i<4;i++){
        float hc = fcomp(hv, i);
        fma4(qa[i][0],hc,w0); fma4(qa[i][1],hc,w1); fma4(qa[i][2],hc,w2); fma4(qa[i][3],hc,w3);
      }
    }
  }
  // rope + elu (head=j, hd=4c0+q)
  #pragma unroll
  for (int i=0;i<4;i++){
    int n = n0 + 4*rr + i;
    int nc = (n < Nz) ? n : 0;
    float co0 = cost[nc*32 + 2*c0], si0 = sint[nc*32 + 2*c0];
    float co1 = cost[nc*32 + 2*c0+1], si1 = sint[nc*32 + 2*c0+1];
    #pragma unroll
    for (int j=0;j<4;j++){
      float4 qi = qa[i][j];
      float4 qo;
      qo.x = elu1(qi.x*co0 - qi.y*si0);
      qo.y = elu1(qi.x*si0 + qi.y*co0);
      qo.z = elu1(qi.z*co1 - qi.w*si1);
      qo.w = elu1(qi.z*si1 + qi.w*co1);
      qa[i][j] = qo;
    }
  }
  // z = 1/(qf . ksum + 1e-6) per (row,head), butterfly over the 16 c0-lanes; fold into qa
  {
    float p[4][4];
    #pragma unroll
    for (int i=0;i<4;i++)
      #pragma unroll
      for (int j=0;j<4;j++)
        p[i][j] = dot4(qa[i][j], *(const float4*)(smem + 9344 + j*64 + 4*c0));
    #pragma unroll
    for (int m=1; m<16; m<<=1){
      #pragma unroll
      for (int i=0;i<4;i++)
        #pragma unroll
        for (int j=0;j<4;j++)
          p[i][j] += __shfl_xor(p[i][j], m, 64);
    }
    #pragma unroll
    for (int i=0;i<4;i++)
      #pragma unroll
      for (int j=0;j<4;j++){
        float zv = 1.f/(p[i][j] + 1e-6f);
        qa[i][j].x *= zv; qa[i][j].y *= zv; qa[i][j].z *= zv; qa[i][j].w *= zv;
      }
  }
  float4 oa[4][4];
  #pragma unroll
  for (int i=0;i<4;i++){
    #pragma unroll
    for (int j=0;j<4;j++) oa[i][j]=f4z();
  }
  #pragma unroll
  for (int hh=0; hh<4; hh++){
    const float* Ph = pmat + (size_t)(b*Hz+hh)*16384;
    float4 ppre[4];
    #pragma unroll
    for (int k=0;k<4;k++) ppre[k] = ((const float4*)(Ph + (size_t)(wr0+4*k)*256))[cf0];
    __syncthreads();    // prev head compute done: qzT & W free
    // conflict-free scatter: register-transpose rows into b128 stores, stride 65
    #pragma unroll
    for (int q=0;q<4;q++){
      float4 rv;
      rv.x = fcomp(qa[0][hh],q); rv.y = fcomp(qa[1][hh],q);
      rv.z = fcomp(qa[2][hh],q); rv.w = fcomp(qa[3][hh],q);
      *(float4*)(smem + 5184 + (4*c0+q)*65 + 4*rr) = rv;
    }
    for (int kt2=0; kt2<64; kt2+=16){
      if (kt2) __syncthreads();
      #pragma unroll
      for (int k=0;k<4;k++) ((float4*)smem)[(wr0+4*k)*64+cf0] = ppre[k];
      if (kt2+16 < 64){
        #pragma unroll
        for (int k=0;k<4;k++) ppre[k] = ((const float4*)(Ph + (size_t)(kt2+16+wr0+4*k)*256))[cf0];
      }
      __syncthreads();
      for (int kk=0; kk<16; kk++){
        float4 av = *(const float4*)(smem + 5184 + (kt2+kk)*65 + 4*rr);
        const float4* wrow = (const float4*)smem + kk*64;
        float4 w0=wrow[c0], w1=wrow[c0+16], w2=wrow[c0+32], w3=wrow[c0+48];
        #pragma unroll
        for (int i=0;i<4;i++){
          float ac = fcomp(av, i);
          fma4(oa[i][0],ac,w0); fma4(oa[i][1],ac,w1); fma4(oa[i][2],ac,w2); fma4(oa[i][3],ac,w3);
        }
      }
    }
  }
  #pragma unroll
  for (int i=0;i<4;i++){
    int n = n0 + 4*rr + i;
    if (n < Nz){
      float4* hp = (float4*)(hb + (size_t)n*Dz);
      #pragma unroll
      for (int j=0;j<4;j++){
        float4 hv = hp[c0+16*j];
        hv.x += oa[i][j].x; hv.y += oa[i][j].y; hv.z += oa[i][j].z; hv.w += oa[i][j].w;
        hp[c0+16*j] = hv;
      }
    }
  }
}

__global__ __launch_bounds__(256) void k_wkv(const float* __restrict__ h,
    const float* __restrict__ Wwk, const float* __restrict__ Wwv,
    float* __restrict__ wkbuf, float* __restrict__ wvbuf){
  __shared__ float wtL[16*257];
  int t = threadIdx.x;
  int b = blockIdx.y, m0 = blockIdx.x*16;
  const float* hb = h + ((size_t)b*Nz + (Nz-64))*Dz;
  for (int i=t;i<16*Dz;i+=256){ int r=i>>8,c=i&255; wtL[r*257+c] = hb[(size_t)(m0+r)*Dz + c]; }
  __syncthreads();
  int r=t>>4, c0=t&15;
  float4 ak0=f4z(),ak1=f4z(),av0=f4z(),av1=f4z();
  for (int kk=0;kk<Dz;kk++){
    float hv = wtL[r*257+kk];
    const float4* wk4 = (const float4*)(Wwk + (size_t)kk*DCz);
    const float4* wv4 = (const float4*)(Wwv + (size_t)kk*DCz);
    fma4(ak0,hv,wk4[c0]); fma4(ak1,hv,wk4[c0+16]);
    fma4(av0,hv,wv4[c0]); fma4(av1,hv,wv4[c0+16]);
  }
  float4* ok = (float4*)(wkbuf + (size_t)(b*64 + m0+r)*DCz);
  float4* ov = (float4*)(wvbuf + (size_t)(b*64 + m0+r)*DCz);
  ok[c0]=ak0; ok[c0+16]=ak1; ov[c0]=av0; ov[c0+16]=av1;
}

__global__ __launch_bounds__(256) void k_cache_upd(float* __restrict__ cache,
    const float* __restrict__ wkbuf, const float* __restrict__ wvbuf,
    const float* __restrict__ Wwg, const float* __restrict__ bwg,
    int s0, int it, int pas){
  __shared__ float sqL[16*132];
  __shared__ float wkL[64*132];
  __shared__ float wat[16*68];
  __shared__ float ncL[16*132];
  __shared__ float wg[16];
  int t = threadIdx.x; int b = blockIdx.x;
  for (int i=t;i<16*DCz;i+=256){ int k2=i>>7,c=i&127; sqL[k2*132+c] = cache[((size_t)(b*NSLOTz)+s0+k2)*DSLOTz + c]; }
  for (int i=t;i<64*DCz;i+=256){ int m=i>>7,c=i&127; wkL[m*132+c] = wkbuf[(size_t)(b*64+m)*DCz+c]; }
  __syncthreads();
  {
    int k2 = t>>4;
    const float4* s4 = (const float4*)(sqL) + k2*33;
    for (int mm=0;mm<4;mm++){
      int m = (t&15) + 16*mm;
      const float4* k4 = (const float4*)(wkL) + m*33;
      float a=0.f;
      for (int d4=0;d4<32;d4++) a += dot4(s4[d4], k4[d4]);
      wat[k2*68+m] = a * 0.088388347648318447f;
    }
  }
  __syncthreads();
  if (t<16){
    float mx=-1e30f;
    for (int m=0;m<64;m++) mx = fmaxf(mx, wat[t*68+m]);
    float su=0.f;
    for (int m=0;m<64;m++){ float e=__expf(wat[t*68+m]-mx); wat[t*68+m]=e; su+=e; }
    float inv=1.f/su;
    for (int m=0;m<64;m++) wat[t*68+m]*=inv;
  }
  __syncthreads();
  {
    int k2=t>>4, c0=t&15;
    float4 a0=f4z(), a1=f4z();
    const float4* wvg = (const float4*)(wvbuf + (size_t)b*64*DCz);
    for (int m=0;m<64;m++){
      float a = wat[k2*68+m];
      fma4(a0,a,wvg[m*32+c0]); fma4(a1,a,wvg[m*32+c0+16]);
    }
    ((float4*)ncL)[k2*33+c0]=a0; ((float4*)ncL)[k2*33+16+c0]=a1;
  }
  __syncthreads();
  if (t<16){
    float a = bwg[0];
    for (int d2=0; d2<DCz; d2++) a += sqL[t*132+d2]*Wwg[d2] + ncL[t*132+d2]*Wwg[DCz+d2];
    wg[t] = sigm(a);
  }
  __syncthreads();
  for (int i=t;i<16*DCz;i+=256){
    int k2=i>>7,c=i&127;
    cache[((size_t)(b*NSLOTz)+s0+k2)*DSLOTz + c] = sqL[k2*132+c] + wg[k2]*ncL[k2*132+c];
  }
  if (t<16){
    float* cp = cache + ((size_t)(b*NSLOTz)+s0+t)*DSLOTz;
    cp[128] = wg[t];
    cp[137] = (it==0)?1.f:0.f; cp[138] = (it==1)?1.f:0.f; cp[139]=0.f; cp[140]=0.f;
    cp[141] = (pas==0)?1.f:0.f; cp[142] = (pas==1)?1.f:0.f; cp[143]=0.f; cp[144]=0.f;
  }
}

__global__ __launch_bounds__(256) void k_logits(const float* __restrict__ h,
    const float* __restrict__ Wout, const float* __restrict__ bout, float* __restrict__ out){
  __shared__ float hl[16*257];
  int t = threadIdx.x; int row0 = blockIdx.x*16;
  for (int i=t;i<16*Dz;i+=256){
    int rr=i>>8,c=i&255; int row=row0+rr; int b=row/Sz, s=row-b*Sz;
    hl[rr*257+c] = h[((size_t)b*Nz + TSz + s)*Dz + c];
  }
  __syncthreads();
  int rr = t>>4, v = t&15;
  float a = bout[v];
  for (int c=0;c<Dz;c++) a += hl[rr*257+c]*Wout[c*Vz + v];
  out[(size_t)(row0+rr)*Vz + v] = a;
}

__global__ __launch_bounds__(256) void k_feedback(float* __restrict__ h,
    const float* __restrict__ logits0, const float* __restrict__ pae,
    const float* __restrict__ Wfb, const float* __restrict__ bfb){
  __shared__ float trL[16*257];
  __shared__ float paeL[16*257];
  __shared__ int amL[16];
  int t = threadIdx.x; int b = blockIdx.y; int s0 = blockIdx.x*16;
  if (t<16){
    int s = s0+t; int am=0;
    if (s < Sz){
      const float* lg = logits0 + (size_t)(b*Sz+s)*Vz;
      float best = lg[0];
      for (int v=1;v<16;v++){ if (lg[v] > best){ best=lg[v]; am=v; } }
    }
    amL[t]=am;
  }
  for (int i=t;i<16*Dz;i+=256){
    int rr=i>>8,c=i&255; int s=s0+rr;
    trL[rr*257+c] = (s<Sz)? h[((size_t)b*Nz + TSz + s)*Dz + c] : 0.f;
  }
  __syncthreads();
  for (int i=t;i<16*Dz;i+=256){ int rr=i>>8,c=i&255; paeL[rr*257+c] = pae[(size_t)amL[rr]*Dz + c]; }
  __syncthreads();
  int r=t>>4, c0=t&15;
  float4 acc[4]; acc[0]=f4z(); acc[1]=f4z(); acc[2]=f4z(); acc[3]=f4z();
  for (int kk=0;kk<Dz;kk++){
    float xv = trL[r*257+kk];
    const float4* wr = (const float4*)(Wfb + (size_t)kk*Dz);
    fma4(acc[0],xv,wr[c0]); fma4(acc[1],xv,wr[c0+16]); fma4(acc[2],xv,wr[c0+32]); fma4(acc[3],xv,wr[c0+48]);
  }
  for (int kk=0;kk<Dz;kk++){
    float xv = paeL[r*257+kk];
    const float4* wr = (const float4*)(Wfb + (size_t)(Dz+kk)*Dz);
    fma4(acc[0],xv,wr[c0]); fma4(acc[1],xv,wr[c0+16]); fma4(acc[2],xv,wr[c0+32]); fma4(acc[3],xv,wr[c0+48]);
  }
  int s = s0+r;
  if (s < Sz){
    float* cp = h + ((size_t)b*Nz + TSz + s)*Dz;
    #pragma unroll
    for (int j=0;j<4;j++){
      float vals[4] = {acc[j].x, acc[j].y, acc[j].z, acc[j].w};
      #pragma unroll
      for (int q2=0;q2<4;q2++){
        int c = (c0+16*j)*4 + q2;
        float g = sigm(vals[q2] + bfb[c]);
        cp[c] = trL[r*257+c] + g*paeL[r*257+c];
      }
    }
  }
}

extern "C" void kernel_launch(void* const* d_in, const int* in_sizes, int n_in,
                              void* d_out, int out_size, void* d_ws, size_t ws_size,
                              hipStream_t stream){
  (void)in_sizes; (void)n_in;
  const int*   demo_in   = (const int*)d_in[0];
  const int*   demo_out  = (const int*)d_in[1];
  const int*   test_in   = (const int*)d_in[2];
  const float* token_emb = (const float*)d_in[3];
  const float* seg_emb   = (const float*)d_in[4];
  const float* slot_emb  = (const float*)d_in[5];
  const float* lid_emb   = (const float*)d_in[6];
  const float* Wq_read   = (const float*)d_in[7];
  const float* Wk_read   = (const float*)d_in[8];
  const float* Wv_read   = (const float*)d_in[9];
  const float* Wg_read   = (const float*)d_in[10];
  const float* bg_read   = (const float*)d_in[11];
  const float* Wqkv      = (const float*)d_in[12];
  const float* Wo        = (const float*)d_in[13];
  const float* Wwk       = (const float*)d_in[14];
  const float* Wwv       = (const float*)d_in[15];
  const float* Wwg       = (const float*)d_in[16];
  const float* bwg       = (const float*)d_in[17];
  const float* Wout      = (const float*)d_in[18];
  const float* bout      = (const float*)d_in[19];
  const float* pae       = (const float*)d_in[20];
  const float* Wfb       = (const float*)d_in[21];
  const float* bfb       = (const float*)d_in[22];

  char* wsb = (char*)d_ws;
  size_t off = 0;
  auto alloc = [&](size_t bytes)->char*{
    char* p = wsb + off;
    off += (bytes + 255) & ~(size_t)255;
    return p;
  };
  float* hbuf   = (float*)alloc((size_t)Bz*Nz*Dz*4);
  float* kread  = (float*)alloc((size_t)Bz*NSLOTz*DCz*4);
  float* vread  = (float*)alloc((size_t)Bz*NSLOTz*Dz*4);
  float* cache  = (float*)alloc((size_t)Bz*NSLOTz*DSLOTz*4);
  float* kvbuf  = (float*)alloc((size_t)Bz*Hz*4160*4);
  float* pmat   = (float*)alloc((size_t)Bz*Hz*64*256*4);
  float* wkbuf  = (float*)alloc((size_t)Bz*64*DCz*4);
  float* wvbuf  = (float*)alloc((size_t)Bz*64*DCz*4);
  float* logits0= (float*)alloc((size_t)Bz*Sz*Vz*4);
  float* cost   = (float*)alloc((size_t)Nz*32*4);
  float* sint   = (float*)alloc((size_t)Nz*32*4);

  if (off > ws_size){
    k_sentinel<<<(out_size+255)/256, 256, 0, stream>>>((float*)d_out, out_size);
    return;
  }

  k_rope<<<(Nz*32+255)/256, 256, 0, stream>>>(cost, sint);
  k_cache_init<<<(Bz*NSLOTz*DSLOTz+255)/256, 256, 0, stream>>>(slot_emb, lid_emb, cache);

  const int KVN = Bz*Hz*4160;
  for (int pas=0; pas<2; pas++){
    k_embed<<<(Bz*Nz*64+255)/256, 256, 0, stream>>>(demo_in, demo_out, test_in, token_emb, seg_emb, hbuf);
    if (pas==1)
      k_feedback<<<dim3(57,Bz), 256, 0, stream>>>(hbuf, logits0, pae, Wfb, bfb);
    for (int l=0; l<3; l++){
      for (int it=0; it<2; it++){
        k_proj_cache<<<Bz*NSLOTz, 384, 0, stream>>>(cache,
            Wk_read + (size_t)l*DSLOTz*DCz, Wv_read + (size_t)l*DSLOTz*Dz, kread, vread);
        k_read_attn<<<dim3(GXR,Bz), 256, 0, stream>>>(kread, vread,
            Wq_read + (size_t)l*Dz*DCz, Wg_read + (size_t)l*Dz, bg_read + l, hbuf);
        k_zero<<<(KVN+255)/256, 256, 0, stream>>>(kvbuf, KVN);
        k_kv<<<dim3(GXA,Bz), 256, 0, stream>>>(hbuf,
            Wqkv + (size_t)l*Dz*768, cost, sint, kvbuf);
        k_pmat<<<Bz*Hz, 256, 0, stream>>>(kvbuf, Wo + (size_t)l*Dz*Dz, pmat);
        k_att<<<dim3(GXA,Bz), 256, 0, stream>>>(hbuf,
            Wqkv + (size_t)l*Dz*768, kvbuf, pmat, cost, sint);
        k_wkv<<<dim3(4,Bz), 256, 0, stream>>>(hbuf,
            Wwk + (size_t)l*Dz*DCz, Wwv + (size_t)l*Dz*DCz, wkbuf, wvbuf);
        k_cache_upd<<<Bz, 256, 0, stream>>>(cache, wkbuf, wvbuf,
            Wwg + (size_t)l*2*DCz, bwg + l, l*16, it, pas);
      }
    }
    float* outp = (pas==0) ? logits0 : (float*)d_out;
    k_logits<<<900, 256, 0, stream>>>(hbuf, Wout, bout, outp);
  }
}

// Round 8
// 19776.765 us; speedup vs baseline: 1.5220x; 1.0103x over previous
//
#include <hip/hip_runtime.h>
#include <math.h>

#define Bz 16
#define Sz 900
#define Vz 16
#define Dz 256
#define DCz 128
#define Hz 4
#define Nz 6300
#define TSz 5400
#define DSLOTz 145
#define NSLOTz 48
#define GXA 99    // ceil(6300/64) row-blocks for k_kv/k_att
#define GXR 197   // ceil(6300/32) row-blocks for k_read_attn

typedef unsigned short u16;
typedef unsigned int u32;

static __device__ __forceinline__ float sigm(float x){ return 1.0f/(1.0f+__expf(-x)); }
static __device__ __forceinline__ void fma4(float4& a, float s, float4 b){ a.x+=s*b.x; a.y+=s*b.y; a.z+=s*b.z; a.w+=s*b.w; }
static __device__ __forceinline__ float dot4(float4 a, float4 b){ return a.x*b.x + a.y*b.y + a.z*b.z + a.w*b.w; }
static __device__ __forceinline__ float4 f4z(){ float4 z; z.x=0.f; z.y=0.f; z.z=0.f; z.w=0.f; return z; }
static __device__ __forceinline__ float elu1(float x){ return x>0.f ? x+1.f : __expf(x); }
static __device__ __forceinline__ float fcomp(float4 v, int i){ return (i==0)?v.x:(i==1)?v.y:(i==2)?v.z:v.w; }

__global__ void k_sentinel(float* out, int nelem){
  int i = blockIdx.x*256 + threadIdx.x;
  if (i < nelem) out[i] = 12345.0f;
}

__global__ void k_rope(float* cost, float* sint){
  int i = blockIdx.x*256 + threadIdx.x;
  if (i >= Nz*32) return;
  int n = i>>5, f = i&31;
  double invd = pow(10000.0, -(double)f/32.0);
  double fr = (double)n * invd;
  cost[i] = (float)cos(fr);
  sint[i] = (float)sin(fr);
}

__global__ void k_embed(const int* __restrict__ di, const int* __restrict__ dq,
                        const int* __restrict__ ti, const float* __restrict__ temb,
                        const float* __restrict__ semb, float* __restrict__ h){
  int i = blockIdx.x*256 + threadIdx.x;   // over B*N*64 float4s
  if (i >= Bz*Nz*64) return;
  int dv = i & 63; int bn = i >> 6; int n = bn % Nz; int b = bn / Nz;
  int tok;
  if (n < TSz){
    int nd = n/1800; int r = n - nd*1800;
    tok = (r < Sz) ? di[(b*3+nd)*Sz + r] : dq[(b*3+nd)*Sz + (r-Sz)];
  } else {
    tok = ti[b*Sz + (n-TSz)];
  }
  const float4* e4 = (const float4*)(temb + (size_t)tok*Dz);
  const float4* s4 = (const float4*)semb;
  float4 v = e4[dv]; float4 s = s4[dv];
  v.x += s.x; v.y += s.y; v.z += s.z; v.w += s.w;
  ((float4*)h)[(size_t)bn*64 + dv] = v;
}

__global__ void k_cache_init(const float* __restrict__ slot_emb, const float* __restrict__ lid,
                             float* __restrict__ cache){
  int i = blockIdx.x*256 + threadIdx.x;
  if (i >= Bz*NSLOTz*DSLOTz) return;
  int c = i % DSLOTz; int sc = (i / DSLOTz) % NSLOTz; int l = sc >> 4;
  float v = 0.f;
  if (c < DCz) v = slot_emb[sc*DCz + c];
  else if (c >= 129 && c < 137) v = lid[l*8 + (c-129)];
  cache[i] = v;
}

// + folds kvbuf zeroing (was k_zero): 768 blocks x 384 thr covers 266240 elems
__global__ __launch_bounds__(384) void k_proj_cache(const float* __restrict__ cache,
    const float* __restrict__ Wk, const float* __restrict__ Wv,
    float* __restrict__ kread, float* __restrict__ vread, float* __restrict__ kvz){
  __shared__ float crow[DSLOTz];
  int b = blockIdx.x / NSLOTz, sc = blockIdx.x % NSLOTz;
  int t = threadIdx.x;
  int zi = blockIdx.x*384 + t;
  if (zi < Bz*Hz*4160) kvz[zi] = 0.f;
  const float* cp = cache + (size_t)(b*NSLOTz+sc)*DSLOTz;
  if (t < DSLOTz) crow[t] = cp[t];
  __syncthreads();
  if (t < DCz){
    float a = 0.f;
    for (int r2=0;r2<DSLOTz;r2++) a += crow[r2]*Wk[r2*DCz + t];
    kread[(size_t)(b*NSLOTz+sc)*DCz + t] = a;
  } else {
    int d = t - DCz;
    float a = 0.f;
    for (int r2=0;r2<DSLOTz;r2++) a += crow[r2]*Wv[r2*Dz + d];
    vread[(size_t)(b*NSLOTz+sc)*Dz + d] = a;
  }
}

// read-attention: 32-row tiles, LDS-staged Wq (K-tile 16), gate fused in GEMM. (r5 version)
#define RA_W 0
#define RA_H 4096
#define RA_G 4672
#define RA_K 4688
#define RA_Q 11024
#define RA_A 15248
__global__ __launch_bounds__(256) void k_read_attn(
    const float* __restrict__ kread, const float* __restrict__ vread,
    const float* __restrict__ Wq, const float* __restrict__ Wg, const float* __restrict__ bg,
    float* __restrict__ h){
  __shared__ float smem[16816];
  const int t = threadIdx.x;
  const int b = blockIdx.y;
  const int n0 = blockIdx.x*32;
  const int c0 = t&15, rr = t>>4;
  float* hb = h + (size_t)b*Nz*Dz;
  for (int id=t; id<1536; id+=256){
    int s=id>>5, d4=id&31;
    ((float4*)(smem+RA_K))[s*33+d4] = ((const float4*)(kread + ((size_t)b*NSLOTz+s)*DCz))[d4];
  }
  float4 qa[2][2];
  qa[0][0]=f4z(); qa[0][1]=f4z(); qa[1][0]=f4z(); qa[1][1]=f4z();
  float gacc0=0.f, gacc1=0.f;
  for (int kt=0; kt<256; kt+=16){
    __syncthreads();
    for (int id=t; id<512; id+=256){
      int wr=id>>5, cf=id&31;
      ((float4*)(smem+RA_W))[wr*32+cf] = ((const float4*)(Wq + (size_t)(kt+wr)*DCz))[cf];
    }
    if (t<128){
      int row=t>>2, u=t&3;
      int n=n0+row;
      float4 hv = (n<Nz)? ((const float4*)(hb + (size_t)n*Dz))[(kt>>2)+u] : f4z();
      float* hp = smem + RA_H + row;
      hp[(4*u+0)*36]=hv.x; hp[(4*u+1)*36]=hv.y; hp[(4*u+2)*36]=hv.z; hp[(4*u+3)*36]=hv.w;
    }
    if (t<16) smem[RA_G+t] = Wg[kt+t];
    __syncthreads();
    for (int kk=0; kk<16; kk++){
      float2 h2 = *(const float2*)(smem + RA_H + kk*36 + 2*rr);
      const float4* wrow = (const float4*)(smem+RA_W) + kk*32;
      float4 w0=wrow[c0], w1=wrow[c0+16];
      float wg = smem[RA_G+kk];
      fma4(qa[0][0],h2.x,w0); fma4(qa[0][1],h2.x,w1);
      fma4(qa[1][0],h2.y,w0); fma4(qa[1][1],h2.y,w1);
      gacc0 += h2.x*wg; gacc1 += h2.y*wg;
    }
  }
  __syncthreads();
  ((float4*)(smem+RA_Q))[(2*rr+0)*33 + c0]      = qa[0][0];
  ((float4*)(smem+RA_Q))[(2*rr+0)*33 + 16 + c0] = qa[0][1];
  ((float4*)(smem+RA_Q))[(2*rr+1)*33 + c0]      = qa[1][0];
  ((float4*)(smem+RA_Q))[(2*rr+1)*33 + 16 + c0] = qa[1][1];
  __syncthreads();
  {
    int row = t&31, sg = t>>5;
    const float4* q4 = (const float4*)(smem+RA_Q) + row*33;
    for (int ss=0; ss<6; ss++){
      int s = sg*6+ss;
      const float4* k4 = (const float4*)(smem+RA_K) + s*33;
      float a=0.f;
      for (int d4=0; d4<32; d4++) a += dot4(q4[d4], k4[d4]);
      smem[RA_A + row*49 + s] = a*0.088388347648318447f;
    }
  }
  __syncthreads();
  if (t<32){
    float* ar = smem + RA_A + t*49;
    float mx=-1e30f;
    for (int s=0;s<48;s++) mx=fmaxf(mx,ar[s]);
    float su=0.f;
    for (int s=0;s<48;s++){ float e=__expf(ar[s]-mx); ar[s]=e; su+=e; }
    float inv=1.f/su;
    for (int s=0;s<48;s++) ar[s]*=inv;
  }
  float4 ov[2][4];
  #pragma unroll
  for (int i=0;i<2;i++){
    #pragma unroll
    for (int j=0;j<4;j++) ov[i][j]=f4z();
  }
  for (int sc=0; sc<3; sc++){
    __syncthreads();
    for (int id=t; id<1024; id+=256){
      int sr=id>>6, cf=id&63;
      ((float4*)(smem+RA_W))[sr*64+cf] = ((const float4*)(vread + ((size_t)b*NSLOTz + sc*16+sr)*Dz))[cf];
    }
    __syncthreads();
    for (int ss=0; ss<16; ss++){
      int s = sc*16+ss;
      float a0 = smem[RA_A + (2*rr+0)*49 + s];
      float a1 = smem[RA_A + (2*rr+1)*49 + s];
      const float4* vrow = (const float4*)(smem+RA_W) + ss*64;
      float4 v0=vrow[c0], v1=vrow[c0+16], v2=vrow[c0+32], v3=vrow[c0+48];
      fma4(ov[0][0],a0,v0); fma4(ov[0][1],a0,v1); fma4(ov[0][2],a0,v2); fma4(ov[0][3],a0,v3);
      fma4(ov[1][0],a1,v0); fma4(ov[1][1],a1,v1); fma4(ov[1][2],a1,v2); fma4(ov[1][3],a1,v3);
    }
  }
  float g0 = sigm(gacc0 + bg[0]);
  float g1 = sigm(gacc1 + bg[0]);
  #pragma unroll
  for (int i=0;i<2;i++){
    int n = n0 + 2*rr + i;
    if (n < Nz){
      float g = i ? g1 : g0;
      float4* hp = (float4*)(hb + (size_t)n*Dz);
      #pragma unroll
      for (int j=0;j<4;j++){
        float4 hv = hp[c0+16*j];
        float4 o = ov[i][j];
        hv.x += g*o.x; hv.y += g*o.y; hv.z += g*o.z; hv.w += g*o.w;
        hp[c0+16*j] = hv;
      }
    }
  }
}

// k/v projection + rope/elu + fused kv accumulation. 64-row tiles, K-tile 16.
// NEW lane map: c0 in [0,32), rr in [0,8): 8 rows x (2 f4 k + 2 f4 v)/lane.
// Reads/kk: 2 hv + 4 w = 6 b128 per 32 fma4 (was 9) — LDS-pipe bound, -33%.
// LDS: W [0,8192) 16x512 ; hT [8192,9280) 16x68 ; P2 reuses kf [0,4352) vh [4352,8704).
__global__ __launch_bounds__(256) void k_kv(const float* __restrict__ h,
    const float* __restrict__ Wl, const float* __restrict__ cost, const float* __restrict__ sint,
    float* __restrict__ kvbuf){
  __shared__ float smem[9280];
  const int t = threadIdx.x;
  const int b = blockIdx.y;
  const int n0 = blockIdx.x*64;
  const int c0 = t&31, rr = t>>5;
  const float* hb = h + (size_t)b*Nz*Dz;
  float4 ka[8][2], va[8][2];
  #pragma unroll
  for (int i=0;i<8;i++){
    #pragma unroll
    for (int j=0;j<2;j++){ ka[i][j]=f4z(); va[i][j]=f4z(); }
  }
  for (int kt=0; kt<256; kt+=16){
    __syncthreads();
    for (int id=t; id<2048; id+=256){
      int wr = id>>7, cf = id&127;
      ((float4*)smem)[wr*128+cf] = ((const float4*)(Wl + (size_t)(kt+wr)*768 + 256))[cf];
    }
    {
      int row = t>>2, u = t&3;
      int n = n0 + row;
      float4 hv = (n<Nz) ? ((const float4*)(hb + (size_t)n*Dz))[(kt>>2)+u] : f4z();
      float* hp = smem + 8192 + row;
      hp[(4*u+0)*68]=hv.x; hp[(4*u+1)*68]=hv.y; hp[(4*u+2)*68]=hv.z; hp[(4*u+3)*68]=hv.w;
    }
    __syncthreads();
    for (int kk=0; kk<16; kk++){
      const float* hT = smem + 8192 + kk*68 + 8*rr;
      float4 hv0 = *(const float4*)hT;
      float4 hv1 = *(const float4*)(hT+4);
      const float4* wrow = (const float4*)smem + kk*128;
      float4 wk0=wrow[c0], wk1=wrow[c0+32];
      float4 wv0=wrow[64+c0], wv1=wrow[64+c0+32];
      #pragma unroll
      for (int i=0;i<8;i++){
        float hc = (i<4) ? fcomp(hv0,i) : fcomp(hv1,i-4);
        fma4(ka[i][0],hc,wk0); fma4(ka[i][1],hc,wk1);
        fma4(va[i][0],hc,wv0); fma4(va[i][1],hc,wv1);
      }
    }
  }
  // rope+elu on k: cols 4*c0+128*j -> head=(c0>>4)+2j, hd=4*(c0&15), fi=2*(c0&15)
  {
    int fi = 2*(c0&15);
    #pragma unroll
    for (int i=0;i<8;i++){
      int n = n0 + 8*rr + i;
      int valid = (n < Nz);
      int nc = valid ? n : 0;
      float co0 = cost[nc*32 + fi], si0 = sint[nc*32 + fi];
      float co1 = cost[nc*32 + fi+1], si1 = sint[nc*32 + fi+1];
      #pragma unroll
      for (int j=0;j<2;j++){
        float4 kin = ka[i][j];
        float r0 = kin.x*co0 - kin.y*si0;
        float r1 = kin.x*si0 + kin.y*co0;
        float r2 = kin.z*co1 - kin.w*si1;
        float r3 = kin.z*si1 + kin.w*co1;
        float4 ko;
        ko.x = valid ? elu1(r0) : 0.f;
        ko.y = valid ? elu1(r1) : 0.f;
        ko.z = valid ? elu1(r2) : 0.f;
        ko.w = valid ? elu1(r3) : 0.f;
        ka[i][j] = ko;
      }
    }
  }
  const int d = t&63, q4 = t>>6;
  float* kvb = kvbuf + (size_t)(b*Hz)*4160;
  #pragma unroll
  for (int g=0; g<4; g++){
    __syncthreads();
    if ((c0>>4) == (g&1)){
      const int jj = g>>1;
      const int dbase = 4*(c0&15);
      #pragma unroll
      for (int i=0;i<8;i++){
        *(float4*)(smem + (8*rr+i)*68 + dbase)        = ka[i][jj];
        *(float4*)(smem + 4352 + (8*rr+i)*68 + dbase) = va[i][jj];
      }
    }
    __syncthreads();
    float4 kvacc[4];
    #pragma unroll
    for (int u=0;u<4;u++) kvacc[u]=f4z();
    float ksl = 0.f;
    for (int row=0; row<64; row++){
      float kd = smem[row*68 + d];
      ksl += kd;
      const float4* vp = (const float4*)(smem + 4352 + row*68);
      #pragma unroll
      for (int u=0;u<4;u++) fma4(kvacc[u], kd, vp[q4*4+u]);
    }
    float* kq = kvb + g*4160;
    #pragma unroll
    for (int u=0;u<4;u++){
      int e = q4*16 + 4*u;
      atomicAdd(&kq[(e+0)*64+d], kvacc[u].x);
      atomicAdd(&kq[(e+1)*64+d], kvacc[u].y);
      atomicAdd(&kq[(e+2)*64+d], kvacc[u].z);
      atomicAdd(&kq[(e+3)*64+d], kvacc[u].w);
    }
    if (q4==0) atomicAdd(&kq[4096+d], ksl);
  }
}

// P[b][h] = kv_h @ Wo_h  (64 x 256, K=64). grid: Bz*Hz blocks.
__global__ __launch_bounds__(256) void k_pmat(const float* __restrict__ kvbuf,
    const float* __restrict__ Wo, float* __restrict__ pmat){
  __shared__ float smem[8448]; // kvL [0,4352) 64x68 ; wT [4352,8448) 16x256
  const int t = threadIdx.x;
  const int bh = blockIdx.x;
  const int hh = bh & 3;
  const int c0 = t&15, rr = t>>4;
  const float* kvp = kvbuf + (size_t)bh*4160;
  for (int id=t; id<4096; id+=256){
    int e=id>>6, d=id&63;
    smem[e*68+d] = kvp[id];
  }
  float4 acc[4][4];
  #pragma unroll
  for (int i=0;i<4;i++){
    #pragma unroll
    for (int j=0;j<4;j++) acc[i][j]=f4z();
  }
  for (int kt=0; kt<64; kt+=16){
    __syncthreads();
    for (int id=t; id<1024; id+=256){
      int wr=id>>6, cf=id&63;
      ((float4*)(smem+4352))[wr*64+cf] = ((const float4*)(Wo + (size_t)(hh*64+kt+wr)*256))[cf];
    }
    __syncthreads();
    for (int kk=0; kk<16; kk++){
      float4 a4 = *(const float4*)(smem + (kt+kk)*68 + 4*rr);
      const float4* wrow = (const float4*)(smem+4352) + kk*64;
      float4 w0=wrow[c0], w1=wrow[c0+16], w2=wrow[c0+32], w3=wrow[c0+48];
      #pragma unroll
      for (int i=0;i<4;i++){
        float ac = fcomp(a4,i);
        fma4(acc[i][0],ac,w0); fma4(acc[i][1],ac,w1); fma4(acc[i][2],ac,w2); fma4(acc[i][3],ac,w3);
      }
    }
  }
  float* Pp = pmat + (size_t)bh*16384;
  #pragma unroll
  for (int i=0;i<4;i++){
    #pragma unroll
    for (int j=0;j<4;j++) ((float4*)Pp)[(4*rr+i)*64 + c0 + 16*j] = acc[i][j];
  }
}

// q projection + rope/elu + z (shuffle) + per-head qz@P GEMM + residual.
// NEW lane map: c0 in [0,32), rr in [0,8): 8 rows x 2 f4-cols/lane.
// Reads/kk: 2 hv + 2 w = 4 b128 per 16 fma4 (was 5). qzT stride 68 (b128-aligned all d).
// LDS: W [0,4096) 16x256 ; hT [4096,5184) 16x68 ; qzT [5184,9536) 64x68 d-major ; ksum [9536,9792)
__global__ __launch_bounds__(256) void k_att(
    float* __restrict__ h, const float* __restrict__ Wq768,
    const float* __restrict__ kvbuf, const float* __restrict__ pmat,
    const float* __restrict__ cost, const float* __restrict__ sint){
  __shared__ float smem[9792];
  const int t = threadIdx.x;
  const int b = blockIdx.y;
  const int n0 = blockIdx.x*64;
  const int c0 = t&31, rr = t>>5;
  float* hb = h + (size_t)b*Nz*Dz;
  smem[9536 + t] = kvbuf[(size_t)(b*Hz + (t>>6))*4160 + 4096 + (t&63)];
  float4 qa[8][2];
  #pragma unroll
  for (int i=0;i<8;i++){ qa[i][0]=f4z(); qa[i][1]=f4z(); }
  for (int kt=0; kt<256; kt+=16){
    __syncthreads();
    for (int id=t; id<1024; id+=256){
      int wr=id>>6, cf=id&63;
      ((float4*)smem)[wr*64+cf] = ((const float4*)(Wq768 + (size_t)(kt+wr)*768))[cf];
    }
    {
      int row=t>>2, u=t&3;
      int n = n0+row;
      float4 hv = (n<Nz)? ((const float4*)(hb + (size_t)n*Dz))[(kt>>2)+u] : f4z();
      float* hp = smem + 4096 + row;
      hp[(4*u+0)*68]=hv.x; hp[(4*u+1)*68]=hv.y; hp[(4*u+2)*68]=hv.z; hp[(4*u+3)*68]=hv.w;
    }
    __syncthreads();
    for (int kk=0; kk<16; kk++){
      const float* hT = smem + 4096 + kk*68 + 8*rr;
      float4 hv0 = *(const float4*)hT;
      float4 hv1 = *(const float4*)(hT+4);
      const float4* wrow = (const float4*)smem + kk*64;
      float4 w0=wrow[c0], w1=wrow[c0+32];
      #pragma unroll
      for (int i=0;i<8;i++){
        float hc = (i<4) ? fcomp(hv0,i) : fcomp(hv1,i-4);
        fma4(qa[i][0],hc,w0); fma4(qa[i][1],hc,w1);
      }
    }
  }
  // rope + elu: cols 4*c0+128j -> head=(c0>>4)+2j, hd=4*(c0&15), fi=2*(c0&15)
  {
    int fi = 2*(c0&15);
    #pragma unroll
    for (int i=0;i<8;i++){
      int n = n0 + 8*rr + i;
      int nc = (n < Nz) ? n : 0;
      float co0 = cost[nc*32 + fi], si0 = sint[nc*32 + fi];
      float co1 = cost[nc*32 + fi+1], si1 = sint[nc*32 + fi+1];
      #pragma unroll
      for (int j=0;j<2;j++){
        float4 qi = qa[i][j];
        float4 qo;
        qo.x = elu1(qi.x*co0 - qi.y*si0);
        qo.y = elu1(qi.x*si0 + qi.y*co0);
        qo.z = elu1(qi.z*co1 - qi.w*si1);
        qo.w = elu1(qi.z*si1 + qi.w*co1);
        qa[i][j] = qo;
      }
    }
  }
  // z = 1/(qf.ksum + 1e-6) per (row, head): partial dot, butterfly over c0 bits 0-3
  {
    float p[8][2];
    #pragma unroll
    for (int i=0;i<8;i++)
      #pragma unroll
      for (int j=0;j<2;j++)
        p[i][j] = dot4(qa[i][j], *(const float4*)(smem + 9536 + ((c0>>4)+2*j)*64 + 4*(c0&15)));
    #pragma unroll
    for (int m=1; m<16; m<<=1){
      #pragma unroll
      for (int i=0;i<8;i++)
        #pragma unroll
        for (int j=0;j<2;j++)
          p[i][j] += __shfl_xor(p[i][j], m, 64);
    }
    #pragma unroll
    for (int i=0;i<8;i++)
      #pragma unroll
      for (int j=0;j<2;j++){
        float zv = 1.f/(p[i][j] + 1e-6f);
        qa[i][j].x *= zv; qa[i][j].y *= zv; qa[i][j].z *= zv; qa[i][j].w *= zv;
      }
  }
  float4 oa[8][2];
  #pragma unroll
  for (int i=0;i<8;i++){ oa[i][0]=f4z(); oa[i][1]=f4z(); }
  #pragma unroll
  for (int hh=0; hh<4; hh++){
    __syncthreads();    // prev compute done: qzT & W free
    if ((c0>>4) == (hh&1)){
      const int jj = hh>>1;
      const int dbase = 4*(c0&15);
      #pragma unroll
      for (int q=0;q<4;q++){
        float4 lo, hi;
        lo.x=fcomp(qa[0][jj],q); lo.y=fcomp(qa[1][jj],q); lo.z=fcomp(qa[2][jj],q); lo.w=fcomp(qa[3][jj],q);
        hi.x=fcomp(qa[4][jj],q); hi.y=fcomp(qa[5][jj],q); hi.z=fcomp(qa[6][jj],q); hi.w=fcomp(qa[7][jj],q);
        float* qz = smem + 5184 + (dbase+q)*68 + 8*rr;
        *(float4*)qz = lo;
        *(float4*)(qz+4) = hi;
      }
    }
    const float* Ph = pmat + (size_t)(b*Hz+hh)*16384;
    for (int kt2=0; kt2<64; kt2+=16){
      if (kt2) __syncthreads();
      for (int id=t; id<1024; id+=256){
        int wr=id>>6, cf=id&63;
        ((float4*)smem)[wr*64+cf] = ((const float4*)(Ph + (size_t)(kt2+wr)*256))[cf];
      }
      __syncthreads();
      for (int kk=0; kk<16; kk++){
        const float* qz = smem + 5184 + (kt2+kk)*68 + 8*rr;
        float4 av0 = *(const float4*)qz;
        float4 av1 = *(const float4*)(qz+4);
        const float4* wrow = (const float4*)smem + kk*64;
        float4 w0=wrow[c0], w1=wrow[c0+32];
        #pragma unroll
        for (int i=0;i<8;i++){
          float ac = (i<4) ? fcomp(av0,i) : fcomp(av1,i-4);
          fma4(oa[i][0],ac,w0); fma4(oa[i][1],ac,w1);
        }
      }
    }
  }
  #pragma unroll
  for (int i=0;i<8;i++){
    int n = n0 + 8*rr + i;
    if (n < Nz){
      float4* hp = (float4*)(hb + (size_t)n*Dz);
      float4 hv0 = hp[c0];
      hv0.x += oa[i][0].x; hv0.y += oa[i][0].y; hv0.z += oa[i][0].z; hv0.w += oa[i][0].w;
      hp[c0] = hv0;
      float4 hv1 = hp[c0+32];
      hv1.x += oa[i][1].x; hv1.y += oa[i][1].y; hv1.z += oa[i][1].z; hv1.w += oa[i][1].w;
      hp[c0+32] = hv1;
    }
  }
}

__global__ __launch_bounds__(256) void k_wkv(const float* __restrict__ h,
    const float* __restrict__ Wwk, const float* __restrict__ Wwv,
    float* __restrict__ wkbuf, float* __restrict__ wvbuf){
  __shared__ float wtL[16*257];
  int t = threadIdx.x;
  int b = blockIdx.y, m0 = blockIdx.x*16;
  const float* hb = h + ((size_t)b*Nz + (Nz-64))*Dz;
  for (int i=t;i<16*Dz;i+=256){ int r=i>>8,c=i&255; wtL[r*257+c] = hb[(size_t)(m0+r)*Dz + c]; }
  __syncthreads();
  int r=t>>4, c0=t&15;
  float4 ak0=f4z(),ak1=f4z(),av0=f4z(),av1=f4z();
  for (int kk=0;kk<Dz;kk++){
    float hv = wtL[r*257+kk];
    const float4* wk4 = (const float4*)(Wwk + (size_t)kk*DCz);
    const float4* wv4 = (const float4*)(Wwv + (size_t)kk*DCz);
    fma4(ak0,hv,wk4[c0]); fma4(ak1,hv,wk4[c0+16]);
    fma4(av0,hv,wv4[c0]); fma4(av1,hv,wv4[c0+16]);
  }
  float4* ok = (float4*)(wkbuf + (size_t)(b*64 + m0+r)*DCz);
  float4* ov = (float4*)(wvbuf + (size_t)(b*64 + m0+r)*DCz);
  ok[c0]=ak0; ok[c0+16]=ak1; ov[c0]=av0; ov[c0+16]=av1;
}

__global__ __launch_bounds__(256) void k_cache_upd(float* __restrict__ cache,
    const float* __restrict__ wkbuf, const float* __restrict__ wvbuf,
    const float* __restrict__ Wwg, const float* __restrict__ bwg,
    int s0, int it, int pas){
  __shared__ float sqL[16*132];
  __shared__ float wkL[64*132];
  __shared__ float wat[16*68];
  __shared__ float ncL[16*132];
  __shared__ float wg[16];
  int t = threadIdx.x; int b = blockIdx.x;
  for (int i=t;i<16*DCz;i+=256){ int k2=i>>7,c=i&127; sqL[k2*132+c] = cache[((size_t)(b*NSLOTz)+s0+k2)*DSLOTz + c]; }
  for (int i=t;i<64*DCz;i+=256){ int m=i>>7,c=i&127; wkL[m*132+c] = wkbuf[(size_t)(b*64+m)*DCz+c]; }
  __syncthreads();
  {
    int k2 = t>>4;
    const float4* s4 = (const float4*)(sqL) + k2*33;
    for (int mm=0;mm<4;mm++){
      int m = (t&15) + 16*mm;
      const float4* k4 = (const float4*)(wkL) + m*33;
      float a=0.f;
      for (int d4=0;d4<32;d4++) a += dot4(s4[d4], k4[d4]);
      wat[k2*68+m] = a * 0.088388347648318447f;
    }
  }
  __syncthreads();
  if (t<16){
    float mx=-1e30f;
    for (int m=0;m<64;m++) mx = fmaxf(mx, wat[t*68+m]);
    float su=0.f;
    for (int m=0;m<64;m++){ float e=__expf(wat[t*68+m]-mx); wat[t*68+m]=e; su+=e; }
    float inv=1.f/su;
    for (int m=0;m<64;m++) wat[t*68+m]*=inv;
  }
  __syncthreads();
  {
    int k2=t>>4, c0=t&15;
    float4 a0=f4z(), a1=f4z();
    const float4* wvg = (const float4*)(wvbuf + (size_t)b*64*DCz);
    for (int m=0;m<64;m++){
      float a = wat[k2*68+m];
      fma4(a0,a,wvg[m*32+c0]); fma4(a1,a,wvg[m*32+c0+16]);
    }
    ((float4*)ncL)[k2*33+c0]=a0; ((float4*)ncL)[k2*33+16+c0]=a1;
  }
  __syncthreads();
  if (t<16){
    float a = bwg[0];
    for (int d2=0; d2<DCz; d2++) a += sqL[t*132+d2]*Wwg[d2] + ncL[t*132+d2]*Wwg[DCz+d2];
    wg[t] = sigm(a);
  }
  __syncthreads();
  for (int i=t;i<16*DCz;i+=256){
    int k2=i>>7,c=i&127;
    cache[((size_t)(b*NSLOTz)+s0+k2)*DSLOTz + c] = sqL[k2*132+c] + wg[k2]*ncL[k2*132+c];
  }
  if (t<16){
    float* cp = cache + ((size_t)(b*NSLOTz)+s0+t)*DSLOTz;
    cp[128] = wg[t];
    cp[137] = (it==0)?1.f:0.f; cp[138] = (it==1)?1.f:0.f; cp[139]=0.f; cp[140]=0.f;
    cp[141] = (pas==0)?1.f:0.f; cp[142] = (pas==1)?1.f:0.f; cp[143]=0.f; cp[144]=0.f;
  }
}

__global__ __launch_bounds__(256) void k_logits(const float* __restrict__ h,
    const float* __restrict__ Wout, const float* __restrict__ bout, float* __restrict__ out){
  __shared__ float hl[16*257];
  int t = threadIdx.x; int row0 = blockIdx.x*16;
  for (int i=t;i<16*Dz;i+=256){
    int rr=i>>8,c=i&255; int row=row0+rr; int b=row/Sz, s=row-b*Sz;
    hl[rr*257+c] = h[((size_t)b*Nz + TSz + s)*Dz + c];
  }
  __syncthreads();
  int rr = t>>4, v = t&15;
  float a = bout[v];
  for (int c=0;c<Dz;c++) a += hl[rr*257+c]*Wout[c*Vz + v];
  out[(size_t)(row0+rr)*Vz + v] = a;
}

__global__ __launch_bounds__(256) void k_feedback(float* __restrict__ h,
    const float* __restrict__ logits0, const float* __restrict__ pae,
    const float* __restrict__ Wfb, const float* __restrict__ bfb){
  __shared__ float trL[16*257];
  __shared__ float paeL[16*257];
  __shared__ int amL[16];
  int t = threadIdx.x; int b = blockIdx.y; int s0 = blockIdx.x*16;
  if (t<16){
    int s = s0+t; int am=0;
    if (s < Sz){
      const float* lg = logits0 + (size_t)(b*Sz+s)*Vz;
      float best = lg[0];
      for (int v=1;v<16;v++){ if (lg[v] > best){ best=lg[v]; am=v; } }
    }
    amL[t]=am;
  }
  for (int i=t;i<16*Dz;i+=256){
    int rr=i>>8,c=i&255; int s=s0+rr;
    trL[rr*257+c] = (s<Sz)? h[((size_t)b*Nz + TSz + s)*Dz + c] : 0.f;
  }
  __syncthreads();
  for (int i=t;i<16*Dz;i+=256){ int rr=i>>8,c=i&255; paeL[rr*257+c] = pae[(size_t)amL[rr]*Dz + c]; }
  __syncthreads();
  int r=t>>4, c0=t&15;
  float4 acc[4]; acc[0]=f4z(); acc[1]=f4z(); acc[2]=f4z(); acc[3]=f4z();
  for (int kk=0;kk<Dz;kk++){
    float xv = trL[r*257+kk];
    const float4* wr = (const float4*)(Wfb + (size_t)kk*Dz);
    fma4(acc[0],xv,wr[c0]); fma4(acc[1],xv,wr[c0+16]); fma4(acc[2],xv,wr[c0+32]); fma4(acc[3],xv,wr[c0+48]);
  }
  for (int kk=0;kk<Dz;kk++){
    float xv = paeL[r*257+kk];
    const float4* wr = (const float4*)(Wfb + (size_t)(Dz+kk)*Dz);
    fma4(acc[0],xv,wr[c0]); fma4(acc[1],xv,wr[c0+16]); fma4(acc[2],xv,wr[c0+32]); fma4(acc[3],xv,wr[c0+48]);
  }
  int s = s0+r;
  if (s < Sz){
    float* cp = h + ((size_t)b*Nz + TSz + s)*Dz;
    #pragma unroll
    for (int j=0;j<4;j++){
      float vals[4] = {acc[j].x, acc[j].y, acc[j].z, acc[j].w};
      #pragma unroll
      for (int q2=0;q2<4;q2++){
        int c = (c0+16*j)*4 + q2;
        float g = sigm(vals[q2] + bfb[c]);
        cp[c] = trL[r*257+c] + g*paeL[r*257+c];
      }
    }
  }
}

extern "C" void kernel_launch(void* const* d_in, const int* in_sizes, int n_in,
                              void* d_out, int out_size, void* d_ws, size_t ws_size,
                              hipStream_t stream){
  (void)in_sizes; (void)n_in;
  const int*   demo_in   = (const int*)d_in[0];
  const int*   demo_out  = (const int*)d_in[1];
  const int*   test_in   = (const int*)d_in[2];
  const float* token_emb = (const float*)d_in[3];
  const float* seg_emb   = (const float*)d_in[4];
  const float* slot_emb  = (const float*)d_in[5];
  const float* lid_emb   = (const float*)d_in[6];
  const float* Wq_read   = (const float*)d_in[7];
  const float* Wk_read   = (const float*)d_in[8];
  const float* Wv_read   = (const float*)d_in[9];
  const float* Wg_read   = (const float*)d_in[10];
  const float* bg_read   = (const float*)d_in[11];
  const float* Wqkv      = (const float*)d_in[12];
  const float* Wo        = (const float*)d_in[13];
  const float* Wwk       = (const float*)d_in[14];
  const float* Wwv       = (const float*)d_in[15];
  const float* Wwg       = (const float*)d_in[16];
  const float* bwg       = (const float*)d_in[17];
  const float* Wout      = (const float*)d_in[18];
  const float* bout      = (const float*)d_in[19];
  const float* pae       = (const float*)d_in[20];
  const float* Wfb       = (const float*)d_in[21];
  const float* bfb       = (const float*)d_in[22];

  char* wsb = (char*)d_ws;
  size_t off = 0;
  auto alloc = [&](size_t bytes)->char*{
    char* p = wsb + off;
    off += (bytes + 255) & ~(size_t)255;
    return p;
  };
  float* hbuf   = (float*)alloc((size_t)Bz*Nz*Dz*4);
  float* kread  = (float*)alloc((size_t)Bz*NSLOTz*DCz*4);
  float* vread  = (float*)alloc((size_t)Bz*NSLOTz*Dz*4);
  float* cache  = (float*)alloc((size_t)Bz*NSLOTz*DSLOTz*4);
  float* kvbuf  = (float*)alloc((size_t)Bz*Hz*4160*4);
  float* pmat   = (float*)alloc((size_t)Bz*Hz*64*256*4);
  float* wkbuf  = (float*)alloc((size_t)Bz*64*DCz*4);
  float* wvbuf  = (float*)alloc((size_t)Bz*64*DCz*4);
  float* logits0= (float*)alloc((size_t)Bz*Sz*Vz*4);
  float* cost   = (float*)alloc((size_t)Nz*32*4);
  float* sint   = (float*)alloc((size_t)Nz*32*4);

  if (off > ws_size){
    k_sentinel<<<(out_size+255)/256, 256, 0, stream>>>((float*)d_out, out_size);
    return;
  }

  k_rope<<<(Nz*32+255)/256, 256, 0, stream>>>(cost, sint);
  k_cache_init<<<(Bz*NSLOTz*DSLOTz+255)/256, 256, 0, stream>>>(slot_emb, lid_emb, cache);

  for (int pas=0; pas<2; pas++){
    k_embed<<<(Bz*Nz*64+255)/256, 256, 0, stream>>>(demo_in, demo_out, test_in, token_emb, seg_emb, hbuf);
    if (pas==1)
      k_feedback<<<dim3(57,Bz), 256, 0, stream>>>(hbuf, logits0, pae, Wfb, bfb);
    for (int l=0; l<3; l++){
      for (int it=0; it<2; it++){
        k_proj_cache<<<Bz*NSLOTz, 384, 0, stream>>>(cache,
            Wk_read + (size_t)l*DSLOTz*DCz, Wv_read + (size_t)l*DSLOTz*Dz, kread, vread, kvbuf);
        k_read_attn<<<dim3(GXR,Bz), 256, 0, stream>>>(kread, vread,
            Wq_read + (size_t)l*Dz*DCz, Wg_read + (size_t)l*Dz, bg_read + l, hbuf);
        k_kv<<<dim3(GXA,Bz), 256, 0, stream>>>(hbuf,
            Wqkv + (size_t)l*Dz*768, cost, sint, kvbuf);
        k_pmat<<<Bz*Hz, 256, 0, stream>>>(kvbuf, Wo + (size_t)l*Dz*Dz, pmat);
        k_att<<<dim3(GXA,Bz), 256, 0, stream>>>(hbuf,
            Wqkv + (size_t)l*Dz*768, kvbuf, pmat, cost, sint);
        k_wkv<<<dim3(4,Bz), 256, 0, stream>>>(hbuf,
            Wwk + (size_t)l*Dz*DCz, Wwv + (size_t)l*Dz*DCz, wkbuf, wvbuf);
        k_cache_upd<<<Bz, 256, 0, stream>>>(cache, wkbuf, wvbuf,
            Wwg + (size_t)l*2*DCz, bwg + l, l*16, it, pas);
      }
    }
    float* outp = (pas==0) ? logits0 : (float*)d_out;
    k_logits<<<900, 256, 0, stream>>>(hbuf, Wout, bout, outp);
  }
}

// Round 9
// 19174.835 us; speedup vs baseline: 1.5697x; 1.0314x over previous
//
#include <hip/hip_runtime.h>
#include <math.h>

#define Bz 16
#define Sz 900
#define Vz 16
#define Dz 256
#define DCz 128
#define Hz 4
#define Nz 6300
#define TSz 5400
#define DSLOTz 145
#define NSLOTz 48
#define GXA 99    // ceil(6300/64) row-blocks for k_kv/k_att
#define GXR 197   // ceil(6300/32) row-blocks for k_read_attn

typedef unsigned short u16;
typedef unsigned int u32;

static __device__ __forceinline__ float sigm(float x){ return 1.0f/(1.0f+__expf(-x)); }
static __device__ __forceinline__ void fma4(float4& a, float s, float4 b){ a.x+=s*b.x; a.y+=s*b.y; a.z+=s*b.z; a.w+=s*b.w; }
static __device__ __forceinline__ float dot4(float4 a, float4 b){ return a.x*b.x + a.y*b.y + a.z*b.z + a.w*b.w; }
static __device__ __forceinline__ float4 f4z(){ float4 z; z.x=0.f; z.y=0.f; z.z=0.f; z.w=0.f; return z; }
static __device__ __forceinline__ float elu1(float x){ return x>0.f ? x+1.f : __expf(x); }
static __device__ __forceinline__ float fcomp(float4 v, int i){ return (i==0)?v.x:(i==1)?v.y:(i==2)?v.z:v.w; }

__global__ void k_sentinel(float* out, int nelem){
  int i = blockIdx.x*256 + threadIdx.x;
  if (i < nelem) out[i] = 12345.0f;
}

__global__ void k_rope(float* cost, float* sint){
  int i = blockIdx.x*256 + threadIdx.x;
  if (i >= Nz*32) return;
  int n = i>>5, f = i&31;
  double invd = pow(10000.0, -(double)f/32.0);
  double fr = (double)n * invd;
  cost[i] = (float)cos(fr);
  sint[i] = (float)sin(fr);
}

__global__ void k_embed(const int* __restrict__ di, const int* __restrict__ dq,
                        const int* __restrict__ ti, const float* __restrict__ temb,
                        const float* __restrict__ semb, float* __restrict__ h){
  int i = blockIdx.x*256 + threadIdx.x;   // over B*N*64 float4s
  if (i >= Bz*Nz*64) return;
  int dv = i & 63; int bn = i >> 6; int n = bn % Nz; int b = bn / Nz;
  int tok;
  if (n < TSz){
    int nd = n/1800; int r = n - nd*1800;
    tok = (r < Sz) ? di[(b*3+nd)*Sz + r] : dq[(b*3+nd)*Sz + (r-Sz)];
  } else {
    tok = ti[b*Sz + (n-TSz)];
  }
  const float4* e4 = (const float4*)(temb + (size_t)tok*Dz);
  const float4* s4 = (const float4*)semb;
  float4 v = e4[dv]; float4 s = s4[dv];
  v.x += s.x; v.y += s.y; v.z += s.z; v.w += s.w;
  ((float4*)h)[(size_t)bn*64 + dv] = v;
}

__global__ void k_cache_init(const float* __restrict__ slot_emb, const float* __restrict__ lid,
                             float* __restrict__ cache){
  int i = blockIdx.x*256 + threadIdx.x;
  if (i >= Bz*NSLOTz*DSLOTz) return;
  int c = i % DSLOTz; int sc = (i / DSLOTz) % NSLOTz; int l = sc >> 4;
  float v = 0.f;
  if (c < DCz) v = slot_emb[sc*DCz + c];
  else if (c >= 129 && c < 137) v = lid[l*8 + (c-129)];
  cache[i] = v;
}

// + folds kvbuf zeroing (was k_zero): 768 blocks x 384 thr covers 266240 elems
__global__ __launch_bounds__(384) void k_proj_cache(const float* __restrict__ cache,
    const float* __restrict__ Wk, const float* __restrict__ Wv,
    float* __restrict__ kread, float* __restrict__ vread, float* __restrict__ kvz){
  __shared__ float crow[DSLOTz];
  int b = blockIdx.x / NSLOTz, sc = blockIdx.x % NSLOTz;
  int t = threadIdx.x;
  int zi = blockIdx.x*384 + t;
  if (zi < Bz*Hz*4160) kvz[zi] = 0.f;
  const float* cp = cache + (size_t)(b*NSLOTz+sc)*DSLOTz;
  if (t < DSLOTz) crow[t] = cp[t];
  __syncthreads();
  if (t < DCz){
    float a = 0.f;
    for (int r2=0;r2<DSLOTz;r2++) a += crow[r2]*Wk[r2*DCz + t];
    kread[(size_t)(b*NSLOTz+sc)*DCz + t] = a;
  } else {
    int d = t - DCz;
    float a = 0.f;
    for (int r2=0;r2<DSLOTz;r2++) a += crow[r2]*Wv[r2*Dz + d];
    vread[(size_t)(b*NSLOTz+sc)*Dz + d] = a;
  }
}

// read-attention: 32-row tiles, LDS-staged Wq (K-tile 16), gate fused in GEMM. (r5 version)
#define RA_W 0
#define RA_H 4096
#define RA_G 4672
#define RA_K 4688
#define RA_Q 11024
#define RA_A 15248
__global__ __launch_bounds__(256) void k_read_attn(
    const float* __restrict__ kread, const float* __restrict__ vread,
    const float* __restrict__ Wq, const float* __restrict__ Wg, const float* __restrict__ bg,
    float* __restrict__ h){
  __shared__ float smem[16816];
  const int t = threadIdx.x;
  const int b = blockIdx.y;
  const int n0 = blockIdx.x*32;
  const int c0 = t&15, rr = t>>4;
  float* hb = h + (size_t)b*Nz*Dz;
  for (int id=t; id<1536; id+=256){
    int s=id>>5, d4=id&31;
    ((float4*)(smem+RA_K))[s*33+d4] = ((const float4*)(kread + ((size_t)b*NSLOTz+s)*DCz))[d4];
  }
  float4 qa[2][2];
  qa[0][0]=f4z(); qa[0][1]=f4z(); qa[1][0]=f4z(); qa[1][1]=f4z();
  float gacc0=0.f, gacc1=0.f;
  for (int kt=0; kt<256; kt+=16){
    __syncthreads();
    for (int id=t; id<512; id+=256){
      int wr=id>>5, cf=id&31;
      ((float4*)(smem+RA_W))[wr*32+cf] = ((const float4*)(Wq + (size_t)(kt+wr)*DCz))[cf];
    }
    if (t<128){
      int row=t>>2, u=t&3;
      int n=n0+row;
      float4 hv = (n<Nz)? ((const float4*)(hb + (size_t)n*Dz))[(kt>>2)+u] : f4z();
      float* hp = smem + RA_H + row;
      hp[(4*u+0)*36]=hv.x; hp[(4*u+1)*36]=hv.y; hp[(4*u+2)*36]=hv.z; hp[(4*u+3)*36]=hv.w;
    }
    if (t<16) smem[RA_G+t] = Wg[kt+t];
    __syncthreads();
    for (int kk=0; kk<16; kk++){
      float2 h2 = *(const float2*)(smem + RA_H + kk*36 + 2*rr);
      const float4* wrow = (const float4*)(smem+RA_W) + kk*32;
      float4 w0=wrow[c0], w1=wrow[c0+16];
      float wg = smem[RA_G+kk];
      fma4(qa[0][0],h2.x,w0); fma4(qa[0][1],h2.x,w1);
      fma4(qa[1][0],h2.y,w0); fma4(qa[1][1],h2.y,w1);
      gacc0 += h2.x*wg; gacc1 += h2.y*wg;
    }
  }
  __syncthreads();
  ((float4*)(smem+RA_Q))[(2*rr+0)*33 + c0]      = qa[0][0];
  ((float4*)(smem+RA_Q))[(2*rr+0)*33 + 16 + c0] = qa[0][1];
  ((float4*)(smem+RA_Q))[(2*rr+1)*33 + c0]      = qa[1][0];
  ((float4*)(smem+RA_Q))[(2*rr+1)*33 + 16 + c0] = qa[1][1];
  __syncthreads();
  {
    int row = t&31, sg = t>>5;
    const float4* q4 = (const float4*)(smem+RA_Q) + row*33;
    for (int ss=0; ss<6; ss++){
      int s = sg*6+ss;
      const float4* k4 = (const float4*)(smem+RA_K) + s*33;
      float a=0.f;
      for (int d4=0; d4<32; d4++) a += dot4(q4[d4], k4[d4]);
      smem[RA_A + row*49 + s] = a*0.088388347648318447f;
    }
  }
  __syncthreads();
  if (t<32){
    float* ar = smem + RA_A + t*49;
    float mx=-1e30f;
    for (int s=0;s<48;s++) mx=fmaxf(mx,ar[s]);
    float su=0.f;
    for (int s=0;s<48;s++){ float e=__expf(ar[s]-mx); ar[s]=e; su+=e; }
    float inv=1.f/su;
    for (int s=0;s<48;s++) ar[s]*=inv;
  }
  float4 ov[2][4];
  #pragma unroll
  for (int i=0;i<2;i++){
    #pragma unroll
    for (int j=0;j<4;j++) ov[i][j]=f4z();
  }
  for (int sc=0; sc<3; sc++){
    __syncthreads();
    for (int id=t; id<1024; id+=256){
      int sr=id>>6, cf=id&63;
      ((float4*)(smem+RA_W))[sr*64+cf] = ((const float4*)(vread + ((size_t)b*NSLOTz + sc*16+sr)*Dz))[cf];
    }
    __syncthreads();
    for (int ss=0; ss<16; ss++){
      int s = sc*16+ss;
      float a0 = smem[RA_A + (2*rr+0)*49 + s];
      float a1 = smem[RA_A + (2*rr+1)*49 + s];
      const float4* vrow = (const float4*)(smem+RA_W) + ss*64;
      float4 v0=vrow[c0], v1=vrow[c0+16], v2=vrow[c0+32], v3=vrow[c0+48];
      fma4(ov[0][0],a0,v0); fma4(ov[0][1],a0,v1); fma4(ov[0][2],a0,v2); fma4(ov[0][3],a0,v3);
      fma4(ov[1][0],a1,v0); fma4(ov[1][1],a1,v1); fma4(ov[1][2],a1,v2); fma4(ov[1][3],a1,v3);
    }
  }
  float g0 = sigm(gacc0 + bg[0]);
  float g1 = sigm(gacc1 + bg[0]);
  #pragma unroll
  for (int i=0;i<2;i++){
    int n = n0 + 2*rr + i;
    if (n < Nz){
      float g = i ? g1 : g0;
      float4* hp = (float4*)(hb + (size_t)n*Dz);
      #pragma unroll
      for (int j=0;j<4;j++){
        float4 hv = hp[c0+16*j];
        float4 o = ov[i][j];
        hv.x += g*o.x; hv.y += g*o.y; hv.z += g*o.z; hv.w += g*o.w;
        hp[c0+16*j] = hv;
      }
    }
  }
}

// k/v projection + rope/elu + fused kv accumulation. (r5 version: K-tile 16, c0 in [0,16))
// LDS: W [0,8192) 16x512 ; hT [8192,9280) 16x68 ; P2 reuses kf [0,4352) vh [4352,8704).
__global__ __launch_bounds__(256) void k_kv(const float* __restrict__ h,
    const float* __restrict__ Wl, const float* __restrict__ cost, const float* __restrict__ sint,
    float* __restrict__ kvbuf){
  __shared__ float smem[9280];
  const int t = threadIdx.x;
  const int b = blockIdx.y;
  const int n0 = blockIdx.x*64;
  const int c0 = t&15, rr = t>>4;
  const float* hb = h + (size_t)b*Nz*Dz;
  float4 ka[4][4], va[4][4];
  #pragma unroll
  for (int i=0;i<4;i++){
    #pragma unroll
    for (int j=0;j<4;j++){ ka[i][j]=f4z(); va[i][j]=f4z(); }
  }
  for (int kt=0; kt<256; kt+=16){
    __syncthreads();
    for (int id=t; id<2048; id+=256){
      int wr = id>>7, cf = id&127;
      ((float4*)smem)[wr*128+cf] = ((const float4*)(Wl + (size_t)(kt+wr)*768 + 256))[cf];
    }
    {
      int row = t>>2, u = t&3;
      int n = n0 + row;
      float4 hv = (n<Nz) ? ((const float4*)(hb + (size_t)n*Dz))[(kt>>2)+u] : f4z();
      float* hp = smem + 8192 + row;
      hp[(4*u+0)*68]=hv.x; hp[(4*u+1)*68]=hv.y; hp[(4*u+2)*68]=hv.z; hp[(4*u+3)*68]=hv.w;
    }
    __syncthreads();
    for (int kk=0; kk<16; kk++){
      float4 hv = *(const float4*)(smem + 8192 + kk*68 + 4*rr);
      const float4* wrow = (const float4*)smem + kk*128;
      float4 wk0=wrow[c0], wk1=wrow[c0+16], wk2=wrow[c0+32], wk3=wrow[c0+48];
      float4 wv0=wrow[64+c0], wv1=wrow[64+c0+16], wv2=wrow[64+c0+32], wv3=wrow[64+c0+48];
      #pragma unroll
      for (int i=0;i<4;i++){
        float hc = fcomp(hv, i);
        fma4(ka[i][0],hc,wk0); fma4(ka[i][1],hc,wk1); fma4(ka[i][2],hc,wk2); fma4(ka[i][3],hc,wk3);
        fma4(va[i][0],hc,wv0); fma4(va[i][1],hc,wv1); fma4(va[i][2],hc,wv2); fma4(va[i][3],hc,wv3);
      }
    }
  }
  #pragma unroll
  for (int i=0;i<4;i++){
    int n = n0 + 4*rr + i;
    int valid = (n < Nz);
    int nc = valid ? n : 0;
    float co0 = cost[nc*32 + 2*c0], si0 = sint[nc*32 + 2*c0];
    float co1 = cost[nc*32 + 2*c0+1], si1 = sint[nc*32 + 2*c0+1];
    #pragma unroll
    for (int j=0;j<4;j++){
      float4 kin = ka[i][j];
      float r0 = kin.x*co0 - kin.y*si0;
      float r1 = kin.x*si0 + kin.y*co0;
      float r2 = kin.z*co1 - kin.w*si1;
      float r3 = kin.z*si1 + kin.w*co1;
      float4 ko;
      ko.x = valid ? elu1(r0) : 0.f;
      ko.y = valid ? elu1(r1) : 0.f;
      ko.z = valid ? elu1(r2) : 0.f;
      ko.w = valid ? elu1(r3) : 0.f;
      ka[i][j] = ko;
    }
  }
  const int d = t&63, q4 = t>>6;
  float* kvb = kvbuf + (size_t)(b*Hz)*4160;
  #pragma unroll
  for (int g=0; g<4; g++){
    __syncthreads();
    #pragma unroll
    for (int i=0;i<4;i++){
      *(float4*)(smem + (4*rr+i)*68 + 4*c0)        = ka[i][g];
      *(float4*)(smem + 4352 + (4*rr+i)*68 + 4*c0) = va[i][g];
    }
    __syncthreads();
    float4 kvacc[4];
    #pragma unroll
    for (int u=0;u<4;u++) kvacc[u]=f4z();
    float ksl = 0.f;
    for (int row=0; row<64; row++){
      float kd = smem[row*68 + d];
      ksl += kd;
      const float4* vp = (const float4*)(smem + 4352 + row*68);
      #pragma unroll
      for (int u=0;u<4;u++) fma4(kvacc[u], kd, vp[q4*4+u]);
    }
    float* kq = kvb + g*4160;
    #pragma unroll
    for (int u=0;u<4;u++){
      int e = q4*16 + 4*u;
      atomicAdd(&kq[(e+0)*64+d], kvacc[u].x);
      atomicAdd(&kq[(e+1)*64+d], kvacc[u].y);
      atomicAdd(&kq[(e+2)*64+d], kvacc[u].z);
      atomicAdd(&kq[(e+3)*64+d], kvacc[u].w);
    }
    if (q4==0) atomicAdd(&kq[4096+d], ksl);
  }
}

// P[b][h] = kv_h @ Wo_h  (64 x 256, K=64). grid: Bz*Hz blocks.
__global__ __launch_bounds__(256) void k_pmat(const float* __restrict__ kvbuf,
    const float* __restrict__ Wo, float* __restrict__ pmat){
  __shared__ float smem[8448]; // kvL [0,4352) 64x68 ; wT [4352,8448) 16x256
  const int t = threadIdx.x;
  const int bh = blockIdx.x;
  const int hh = bh & 3;
  const int c0 = t&15, rr = t>>4;
  const float* kvp = kvbuf + (size_t)bh*4160;
  for (int id=t; id<4096; id+=256){
    int e=id>>6, d=id&63;
    smem[e*68+d] = kvp[id];
  }
  float4 acc[4][4];
  #pragma unroll
  for (int i=0;i<4;i++){
    #pragma unroll
    for (int j=0;j<4;j++) acc[i][j]=f4z();
  }
  for (int kt=0; kt<64; kt+=16){
    __syncthreads();
    for (int id=t; id<1024; id+=256){
      int wr=id>>6, cf=id&63;
      ((float4*)(smem+4352))[wr*64+cf] = ((const float4*)(Wo + (size_t)(hh*64+kt+wr)*256))[cf];
    }
    __syncthreads();
    for (int kk=0; kk<16; kk++){
      float4 a4 = *(const float4*)(smem + (kt+kk)*68 + 4*rr);
      const float4* wrow = (const float4*)(smem+4352) + kk*64;
      float4 w0=wrow[c0], w1=wrow[c0+16], w2=wrow[c0+32], w3=wrow[c0+48];
      #pragma unroll
      for (int i=0;i<4;i++){
        float ac = fcomp(a4,i);
        fma4(acc[i][0],ac,w0); fma4(acc[i][1],ac,w1); fma4(acc[i][2],ac,w2); fma4(acc[i][3],ac,w3);
      }
    }
  }
  float* Pp = pmat + (size_t)bh*16384;
  #pragma unroll
  for (int i=0;i<4;i++){
    #pragma unroll
    for (int j=0;j<4;j++) ((float4*)Pp)[(4*rr+i)*64 + c0 + 16*j] = acc[i][j];
  }
}

// q projection + rope/elu + z (shuffle) + per-head qz@P GEMM + residual. (r7 version)
// Register-prefetched staging; qzT stride 65 with b128 row-transposed scatter (conflict-free).
// LDS: W [0,4096) ; hT [4096,5184) 16x68 ; qzT [5184,9344) 64x65 (d-major) ; ksum [9344,9600)
__global__ __launch_bounds__(256) void k_att(
    float* __restrict__ h, const float* __restrict__ Wq768,
    const float* __restrict__ kvbuf, const float* __restrict__ pmat,
    const float* __restrict__ cost, const float* __restrict__ sint){
  __shared__ float smem[9600];
  const int t = threadIdx.x;
  const int b = blockIdx.y;
  const int n0 = blockIdx.x*64;
  const int c0 = t&15, rr = t>>4;
  const int wr0 = t>>6, cf0 = t&63;     // W staging: rows wr0+4k
  const int hrow = t>>2, hu = t&3;      // h staging
  float* hb = h + (size_t)b*Nz*Dz;
  smem[9344 + t] = kvbuf[(size_t)(b*Hz + (t>>6))*4160 + 4096 + (t&63)];
  float4 wpre[4]; float4 hpre;
  #pragma unroll
  for (int k=0;k<4;k++)
    wpre[k] = ((const float4*)(Wq768 + (size_t)(wr0+4*k)*768))[cf0];
  { int n=n0+hrow; hpre = (n<Nz)? ((const float4*)(hb + (size_t)n*Dz))[hu] : f4z(); }
  float4 qa[4][4];
  #pragma unroll
  for (int i=0;i<4;i++){
    #pragma unroll
    for (int j=0;j<4;j++) qa[i][j]=f4z();
  }
  for (int kt=0; kt<256; kt+=16){
    __syncthreads();
    #pragma unroll
    for (int k=0;k<4;k++) ((float4*)smem)[(wr0+4*k)*64+cf0] = wpre[k];
    { float* hp = smem + 4096 + hrow;
      hp[(4*hu+0)*68]=hpre.x; hp[(4*hu+1)*68]=hpre.y; hp[(4*hu+2)*68]=hpre.z; hp[(4*hu+3)*68]=hpre.w; }
    if (kt+16 < 256){
      #pragma unroll
      for (int k=0;k<4;k++)
        wpre[k] = ((const float4*)(Wq768 + (size_t)(kt+16+wr0+4*k)*768))[cf0];
      int n=n0+hrow; hpre = (n<Nz)? ((const float4*)(hb + (size_t)n*Dz))[((kt+16)>>2)+hu] : f4z();
    }
    __syncthreads();
    for (int kk=0; kk<16; kk++){
      float4 hv = *(const float4*)(smem + 4096 + kk*68 + 4*rr);
      const float4* wrow = (const float4*)smem + kk*64;
      float4 w0=wrow[c0], w1=wrow[c0+16], w2=wrow[c0+32], w3=wrow[c0+48];
      #pragma unroll
      for (int i=0;i<4;i++){
        float hc = fcomp(hv, i);
        fma4(qa[i][0],hc,w0); fma4(qa[i][1],hc,w1); fma4(qa[i][2],hc,w2); fma4(qa[i][3],hc,w3);
      }
    }
  }
  // rope + elu (head=j, hd=4c0+q)
  #pragma unroll
  for (int i=0;i<4;i++){
    int n = n0 + 4*rr + i;
    int nc = (n < Nz) ? n : 0;
    float co0 = cost[nc*32 + 2*c0], si0 = sint[nc*32 + 2*c0];
    float co1 = cost[nc*32 + 2*c0+1], si1 = sint[nc*32 + 2*c0+1];
    #pragma unroll
    for (int j=0;j<4;j++){
      float4 qi = qa[i][j];
      float4 qo;
      qo.x = elu1(qi.x*co0 - qi.y*si0);
      qo.y = elu1(qi.x*si0 + qi.y*co0);
      qo.z = elu1(qi.z*co1 - qi.w*si1);
      qo.w = elu1(qi.z*si1 + qi.w*co1);
      qa[i][j] = qo;
    }
  }
  // z = 1/(qf . ksum + 1e-6) per (row,head), butterfly over the 16 c0-lanes; fold into qa
  {
    float p[4][4];
    #pragma unroll
    for (int i=0;i<4;i++)
      #pragma unroll
      for (int j=0;j<4;j++)
        p[i][j] = dot4(qa[i][j], *(const float4*)(smem + 9344 + j*64 + 4*c0));
    #pragma unroll
    for (int m=1; m<16; m<<=1){
      #pragma unroll
      for (int i=0;i<4;i++)
        #pragma unroll
        for (int j=0;j<4;j++)
          p[i][j] += __shfl_xor(p[i][j], m, 64);
    }
    #pragma unroll
    for (int i=0;i<4;i++)
      #pragma unroll
      for (int j=0;j<4;j++){
        float zv = 1.f/(p[i][j] + 1e-6f);
        qa[i][j].x *= zv; qa[i][j].y *= zv; qa[i][j].z *= zv; qa[i][j].w *= zv;
      }
  }
  float4 oa[4][4];
  #pragma unroll
  for (int i=0;i<4;i++){
    #pragma unroll
    for (int j=0;j<4;j++) oa[i][j]=f4z();
  }
  #pragma unroll
  for (int hh=0; hh<4; hh++){
    const float* Ph = pmat + (size_t)(b*Hz+hh)*16384;
    float4 ppre[4];
    #pragma unroll
    for (int k=0;k<4;k++) ppre[k] = ((const float4*)(Ph + (size_t)(wr0+4*k)*256))[cf0];
    __syncthreads();    // prev head compute done: qzT & W free
    // conflict-free scatter: register-transpose rows into b128 stores, stride 65
    #pragma unroll
    for (int q=0;q<4;q++){
      float4 rv;
      rv.x = fcomp(qa[0][hh],q); rv.y = fcomp(qa[1][hh],q);
      rv.z = fcomp(qa[2][hh],q); rv.w = fcomp(qa[3][hh],q);
      *(float4*)(smem + 5184 + (4*c0+q)*65 + 4*rr) = rv;
    }
    for (int kt2=0; kt2<64; kt2+=16){
      if (kt2) __syncthreads();
      #pragma unroll
      for (int k=0;k<4;k++) ((float4*)smem)[(wr0+4*k)*64+cf0] = ppre[k];
      if (kt2+16 < 64){
        #pragma unroll
        for (int k=0;k<4;k++) ppre[k] = ((const float4*)(Ph + (size_t)(kt2+16+wr0+4*k)*256))[cf0];
      }
      __syncthreads();
      for (int kk=0; kk<16; kk++){
        float4 av = *(const float4*)(smem + 5184 + (kt2+kk)*65 + 4*rr);
        const float4* wrow = (const float4*)smem + kk*64;
        float4 w0=wrow[c0], w1=wrow[c0+16], w2=wrow[c0+32], w3=wrow[c0+48];
        #pragma unroll
        for (int i=0;i<4;i++){
          float ac = fcomp(av, i);
          fma4(oa[i][0],ac,w0); fma4(oa[i][1],ac,w1); fma4(oa[i][2],ac,w2); fma4(oa[i][3],ac,w3);
        }
      }
    }
  }
  #pragma unroll
  for (int i=0;i<4;i++){
    int n = n0 + 4*rr + i;
    if (n < Nz){
      float4* hp = (float4*)(hb + (size_t)n*Dz);
      #pragma unroll
      for (int j=0;j<4;j++){
        float4 hv = hp[c0+16*j];
        hv.x += oa[i][j].x; hv.y += oa[i][j].y; hv.z += oa[i][j].z; hv.w += oa[i][j].w;
        hp[c0+16*j] = hv;
      }
    }
  }
}

__global__ __launch_bounds__(256) void k_wkv(const float* __restrict__ h,
    const float* __restrict__ Wwk, const float* __restrict__ Wwv,
    float* __restrict__ wkbuf, float* __restrict__ wvbuf){
  __shared__ float wtL[16*257];
  int t = threadIdx.x;
  int b = blockIdx.y, m0 = blockIdx.x*16;
  const float* hb = h + ((size_t)b*Nz + (Nz-64))*Dz;
  for (int i=t;i<16*Dz;i+=256){ int r=i>>8,c=i&255; wtL[r*257+c] = hb[(size_t)(m0+r)*Dz + c]; }
  __syncthreads();
  int r=t>>4, c0=t&15;
  float4 ak0=f4z(),ak1=f4z(),av0=f4z(),av1=f4z();
  for (int kk=0;kk<Dz;kk++){
    float hv = wtL[r*257+kk];
    const float4* wk4 = (const float4*)(Wwk + (size_t)kk*DCz);
    const float4* wv4 = (const float4*)(Wwv + (size_t)kk*DCz);
    fma4(ak0,hv,wk4[c0]); fma4(ak1,hv,wk4[c0+16]);
    fma4(av0,hv,wv4[c0]); fma4(av1,hv,wv4[c0+16]);
  }
  float4* ok = (float4*)(wkbuf + (size_t)(b*64 + m0+r)*DCz);
  float4* ov = (float4*)(wvbuf + (size_t)(b*64 + m0+r)*DCz);
  ok[c0]=ak0; ok[c0+16]=ak1; ov[c0]=av0; ov[c0+16]=av1;
}

__global__ __launch_bounds__(256) void k_cache_upd(float* __restrict__ cache,
    const float* __restrict__ wkbuf, const float* __restrict__ wvbuf,
    const float* __restrict__ Wwg, const float* __restrict__ bwg,
    int s0, int it, int pas){
  __shared__ float sqL[16*132];
  __shared__ float wkL[64*132];
  __shared__ float wat[16*68];
  __shared__ float ncL[16*132];
  __shared__ float wg[16];
  int t = threadIdx.x; int b = blockIdx.x;
  for (int i=t;i<16*DCz;i+=256){ int k2=i>>7,c=i&127; sqL[k2*132+c] = cache[((size_t)(b*NSLOTz)+s0+k2)*DSLOTz + c]; }
  for (int i=t;i<64*DCz;i+=256){ int m=i>>7,c=i&127; wkL[m*132+c] = wkbuf[(size_t)(b*64+m)*DCz+c]; }
  __syncthreads();
  {
    int k2 = t>>4;
    const float4* s4 = (const float4*)(sqL) + k2*33;
    for (int mm=0;mm<4;mm++){
      int m = (t&15) + 16*mm;
      const float4* k4 = (const float4*)(wkL) + m*33;
      float a=0.f;
      for (int d4=0;d4<32;d4++) a += dot4(s4[d4], k4[d4]);
      wat[k2*68+m] = a * 0.088388347648318447f;
    }
  }
  __syncthreads();
  if (t<16){
    float mx=-1e30f;
    for (int m=0;m<64;m++) mx = fmaxf(mx, wat[t*68+m]);
    float su=0.f;
    for (int m=0;m<64;m++){ float e=__expf(wat[t*68+m]-mx); wat[t*68+m]=e; su+=e; }
    float inv=1.f/su;
    for (int m=0;m<64;m++) wat[t*68+m]*=inv;
  }
  __syncthreads();
  {
    int k2=t>>4, c0=t&15;
    float4 a0=f4z(), a1=f4z();
    const float4* wvg = (const float4*)(wvbuf + (size_t)b*64*DCz);
    for (int m=0;m<64;m++){
      float a = wat[k2*68+m];
      fma4(a0,a,wvg[m*32+c0]); fma4(a1,a,wvg[m*32+c0+16]);
    }
    ((float4*)ncL)[k2*33+c0]=a0; ((float4*)ncL)[k2*33+16+c0]=a1;
  }
  __syncthreads();
  if (t<16){
    float a = bwg[0];
    for (int d2=0; d2<DCz; d2++) a += sqL[t*132+d2]*Wwg[d2] + ncL[t*132+d2]*Wwg[DCz+d2];
    wg[t] = sigm(a);
  }
  __syncthreads();
  for (int i=t;i<16*DCz;i+=256){
    int k2=i>>7,c=i&127;
    cache[((size_t)(b*NSLOTz)+s0+k2)*DSLOTz + c] = sqL[k2*132+c] + wg[k2]*ncL[k2*132+c];
  }
  if (t<16){
    float* cp = cache + ((size_t)(b*NSLOTz)+s0+t)*DSLOTz;
    cp[128] = wg[t];
    cp[137] = (it==0)?1.f:0.f; cp[138] = (it==1)?1.f:0.f; cp[139]=0.f; cp[140]=0.f;
    cp[141] = (pas==0)?1.f:0.f; cp[142] = (pas==1)?1.f:0.f; cp[143]=0.f; cp[144]=0.f;
  }
}

__global__ __launch_bounds__(256) void k_logits(const float* __restrict__ h,
    const float* __restrict__ Wout, const float* __restrict__ bout, float* __restrict__ out){
  __shared__ float hl[16*257];
  int t = threadIdx.x; int row0 = blockIdx.x*16;
  for (int i=t;i<16*Dz;i+=256){
    int rr=i>>8,c=i&255; int row=row0+rr; int b=row/Sz, s=row-b*Sz;
    hl[rr*257+c] = h[((size_t)b*Nz + TSz + s)*Dz + c];
  }
  __syncthreads();
  int rr = t>>4, v = t&15;
  float a = bout[v];
  for (int c=0;c<Dz;c++) a += hl[rr*257+c]*Wout[c*Vz + v];
  out[(size_t)(row0+rr)*Vz + v] = a;
}

__global__ __launch_bounds__(256) void k_feedback(float* __restrict__ h,
    const float* __restrict__ logits0, const float* __restrict__ pae,
    const float* __restrict__ Wfb, const float* __restrict__ bfb){
  __shared__ float trL[16*257];
  __shared__ float paeL[16*257];
  __shared__ int amL[16];
  int t = threadIdx.x; int b = blockIdx.y; int s0 = blockIdx.x*16;
  if (t<16){
    int s = s0+t; int am=0;
    if (s < Sz){
      const float* lg = logits0 + (size_t)(b*Sz+s)*Vz;
      float best = lg[0];
      for (int v=1;v<16;v++){ if (lg[v] > best){ best=lg[v]; am=v; } }
    }
    amL[t]=am;
  }
  for (int i=t;i<16*Dz;i+=256){
    int rr=i>>8,c=i&255; int s=s0+rr;
    trL[rr*257+c] = (s<Sz)? h[((size_t)b*Nz + TSz + s)*Dz + c] : 0.f;
  }
  __syncthreads();
  for (int i=t;i<16*Dz;i+=256){ int rr=i>>8,c=i&255; paeL[rr*257+c] = pae[(size_t)amL[rr]*Dz + c]; }
  __syncthreads();
  int r=t>>4, c0=t&15;
  float4 acc[4]; acc[0]=f4z(); acc[1]=f4z(); acc[2]=f4z(); acc[3]=f4z();
  for (int kk=0;kk<Dz;kk++){
    float xv = trL[r*257+kk];
    const float4* wr = (const float4*)(Wfb + (size_t)kk*Dz);
    fma4(acc[0],xv,wr[c0]); fma4(acc[1],xv,wr[c0+16]); fma4(acc[2],xv,wr[c0+32]); fma4(acc[3],xv,wr[c0+48]);
  }
  for (int kk=0;kk<Dz;kk++){
    float xv = paeL[r*257+kk];
    const float4* wr = (const float4*)(Wfb + (size_t)(Dz+kk)*Dz);
    fma4(acc[0],xv,wr[c0]); fma4(acc[1],xv,wr[c0+16]); fma4(acc[2],xv,wr[c0+32]); fma4(acc[3],xv,wr[c0+48]);
  }
  int s = s0+r;
  if (s < Sz){
    float* cp = h + ((size_t)b*Nz + TSz + s)*Dz;
    #pragma unroll
    for (int j=0;j<4;j++){
      float vals[4] = {acc[j].x, acc[j].y, acc[j].z, acc[j].w};
      #pragma unroll
      for (int q2=0;q2<4;q2++){
        int c = (c0+16*j)*4 + q2;
        float g = sigm(vals[q2] + bfb[c]);
        cp[c] = trL[r*257+c] + g*paeL[r*257+c];
      }
    }
  }
}

extern "C" void kernel_launch(void* const* d_in, const int* in_sizes, int n_in,
                              void* d_out, int out_size, void* d_ws, size_t ws_size,
                              hipStream_t stream){
  (void)in_sizes; (void)n_in;
  const int*   demo_in   = (const int*)d_in[0];
  const int*   demo_out  = (const int*)d_in[1];
  const int*   test_in   = (const int*)d_in[2];
  const float* token_emb = (const float*)d_in[3];
  const float* seg_emb   = (const float*)d_in[4];
  const float* slot_emb  = (const float*)d_in[5];
  const float* lid_emb   = (const float*)d_in[6];
  const float* Wq_read   = (const float*)d_in[7];
  const float* Wk_read   = (const float*)d_in[8];
  const float* Wv_read   = (const float*)d_in[9];
  const float* Wg_read   = (const float*)d_in[10];
  const float* bg_read   = (const float*)d_in[11];
  const float* Wqkv      = (const float*)d_in[12];
  const float* Wo        = (const float*)d_in[13];
  const float* Wwk       = (const float*)d_in[14];
  const float* Wwv       = (const float*)d_in[15];
  const float* Wwg       = (const float*)d_in[16];
  const float* bwg       = (const float*)d_in[17];
  const float* Wout      = (const float*)d_in[18];
  const float* bout      = (const float*)d_in[19];
  const float* pae       = (const float*)d_in[20];
  const float* Wfb       = (const float*)d_in[21];
  const float* bfb       = (const float*)d_in[22];

  char* wsb = (char*)d_ws;
  size_t off = 0;
  auto alloc = [&](size_t bytes)->char*{
    char* p = wsb + off;
    off += (bytes + 255) & ~(size_t)255;
    return p;
  };
  float* hbuf   = (float*)alloc((size_t)Bz*Nz*Dz*4);
  float* kread  = (float*)alloc((size_t)Bz*NSLOTz*DCz*4);
  float* vread  = (float*)alloc((size_t)Bz*NSLOTz*Dz*4);
  float* cache  = (float*)alloc((size_t)Bz*NSLOTz*DSLOTz*4);
  float* kvbuf  = (float*)alloc((size_t)Bz*Hz*4160*4);
  float* pmat   = (float*)alloc((size_t)Bz*Hz*64*256*4);
  float* wkbuf  = (float*)alloc((size_t)Bz*64*DCz*4);
  float* wvbuf  = (float*)alloc((size_t)Bz*64*DCz*4);
  float* logits0= (float*)alloc((size_t)Bz*Sz*Vz*4);
  float* cost   = (float*)alloc((size_t)Nz*32*4);
  float* sint   = (float*)alloc((size_t)Nz*32*4);

  if (off > ws_size){
    k_sentinel<<<(out_size+255)/256, 256, 0, stream>>>((float*)d_out, out_size);
    return;
  }

  k_rope<<<(Nz*32+255)/256, 256, 0, stream>>>(cost, sint);
  k_cache_init<<<(Bz*NSLOTz*DSLOTz+255)/256, 256, 0, stream>>>(slot_emb, lid_emb, cache);

  for (int pas=0; pas<2; pas++){
    k_embed<<<(Bz*Nz*64+255)/256, 256, 0, stream>>>(demo_in, demo_out, test_in, token_emb, seg_emb, hbuf);
    if (pas==1)
      k_feedback<<<dim3(57,Bz), 256, 0, stream>>>(hbuf, logits0, pae, Wfb, bfb);
    for (int l=0; l<3; l++){
      for (int it=0; it<2; it++){
        k_proj_cache<<<Bz*NSLOTz, 384, 0, stream>>>(cache,
            Wk_read + (size_t)l*DSLOTz*DCz, Wv_read + (size_t)l*DSLOTz*Dz, kread, vread, kvbuf);
        k_read_attn<<<dim3(GXR,Bz), 256, 0, stream>>>(kread, vread,
            Wq_read + (size_t)l*Dz*DCz, Wg_read + (size_t)l*Dz, bg_read + l, hbuf);
        k_kv<<<dim3(GXA,Bz), 256, 0, stream>>>(hbuf,
            Wqkv + (size_t)l*Dz*768, cost, sint, kvbuf);
        k_pmat<<<Bz*Hz, 256, 0, stream>>>(kvbuf, Wo + (size_t)l*Dz*Dz, pmat);
        k_att<<<dim3(GXA,Bz), 256, 0, stream>>>(hbuf,
            Wqkv + (size_t)l*Dz*768, kvbuf, pmat, cost, sint);
        k_wkv<<<dim3(4,Bz), 256, 0, stream>>>(hbuf,
            Wwk + (size_t)l*Dz*DCz, Wwv + (size_t)l*Dz*DCz, wkbuf, wvbuf);
        k_cache_upd<<<Bz, 256, 0, stream>>>(cache, wkbuf, wvbuf,
            Wwg + (size_t)l*2*DCz, bwg + l, l*16, it, pas);
      }
    }
    float* outp = (pas==0) ? logits0 : (float*)d_out;
    k_logits<<<900, 256, 0, stream>>>(hbuf, Wout, bout, outp);
  }
}